// Round 14
// baseline (281.700 us; speedup 1.0000x reference)
//
#include <hip/hip_runtime.h>
#include <hip/hip_bf16.h>
#include <math.h>

#define NB 32          // graphs
#define N_PER 1000
#define TOTALN 32000
#define NE 512000
#define HID 128
#define Dh 64
#define NH 3
#define EPSV 1e-6f
#define W1CH 250       // k_w1 chunks (4 n's each)

typedef __attribute__((ext_vector_type(8))) short bf16x8;
typedef __attribute__((ext_vector_type(4))) float f32x4;

__device__ __forceinline__ float softplusf(float x) {
    return fmaxf(x, 0.0f) + log1pf(expf(-fabsf(x)));
}
__device__ __forceinline__ unsigned short f2b(float f) {
    __hip_bfloat16 h = __float2bfloat16(f);
    return __builtin_bit_cast(unsigned short, h);
}
__device__ __forceinline__ float b2f(unsigned short u) {
    unsigned int x = ((unsigned int)u) << 16;
    return __builtin_bit_cast(float, x);
}

// deg init + pool-accumulator zero
__global__ __launch_bounds__(256) void k_init_deg(float* deg, float* pp) {
    int i = blockIdx.x * 256 + threadIdx.x;
    if (i < TOTALN) deg[i] = 1.0f;   // self loop
    if (i < NB * 128) pp[i] = 0.f;
}

__global__ __launch_bounds__(256) void k_deg(const int* __restrict__ ei, float* deg) {
    int e = blockIdx.x * 256 + threadIdx.x;
    if (e < NE) atomicAdd(&deg[ei[NE + e]], 1.0f);
}

__global__ __launch_bounds__(256) void k_prep(float* __restrict__ d, int* __restrict__ cnt) {
    int i = blockIdx.x * 256 + threadIdx.x;
    if (i < TOTALN) {
        float v = d[i];
        cnt[i] = (int)v - 1;
        d[i] = rsqrtf(v);
    }
}

__global__ __launch_bounds__(256) void k_scan_block(const int* __restrict__ cnt,
                                                    int* __restrict__ rowptr,
                                                    int* __restrict__ bsum) {
    __shared__ int sh[256];
    int t = threadIdx.x;
    int i = blockIdx.x * 256 + t;
    int v = cnt[i];
    sh[t] = v;
    __syncthreads();
    for (int off = 1; off < 256; off <<= 1) {
        int add = (t >= off) ? sh[t - off] : 0;
        __syncthreads();
        sh[t] += add;
        __syncthreads();
    }
    rowptr[i] = sh[t] - v;
    if (t == 255) bsum[blockIdx.x] = sh[255];
}

__global__ void k_scan_tot(int* __restrict__ bsum) {
    if (threadIdx.x == 0) {
        int run = 0;
        for (int i = 0; i < 125; ++i) { int t = bsum[i]; bsum[i] = run; run += t; }
    }
}

__global__ __launch_bounds__(256) void k_scan_add(int* __restrict__ rowptr,
                                                  const int* __restrict__ bsum,
                                                  int* __restrict__ cursor) {
    int i = blockIdx.x * 256 + threadIdx.x;
    int v = rowptr[i] + bsum[blockIdx.x];
    rowptr[i] = v;
    cursor[i] = v;
    if (i == 0) rowptr[TOTALN] = NE;
}

__global__ __launch_bounds__(256) void k_fill(const int* __restrict__ ei,
                                              const float* __restrict__ dinv,
                                              int* __restrict__ cursor,
                                              int* __restrict__ csr_src,
                                              float* __restrict__ csr_w) {
    int e = blockIdx.x * 256 + threadIdx.x;
    if (e < NE) {
        int s = ei[e], d = ei[NE + e];
        int pos = atomicAdd(&cursor[d], 1);
        csr_src[pos] = s;
        csr_w[pos] = dinv[s] * dinv[d];
    }
}

// transpose+convert ALL THREE W[128][128] f32 -> Wt[layer][c][k] bf16 (one launch)
__global__ __launch_bounds__(256) void k_wcvt3(const float* __restrict__ W1,
                                               const float* __restrict__ W2,
                                               const float* __restrict__ W3,
                                               unsigned short* __restrict__ Wt) {
    int i = blockIdx.x * 256 + threadIdx.x;   // 3*16384
    int w = i >> 14, j = i & 16383;
    const float* W = (w == 0) ? W1 : (w == 1) ? W2 : W3;
    int k = j >> 7, c = j & 127;
    Wt[w * 16384 + c * 128 + k] = f2b(W[j]);
}

// Y[32000 x 128](bf16) = X[32000 x 128] @ W ; MFMA 16x16x32 bf16, no LDS.
template<int INF32>
__global__ __launch_bounds__(256) void k_mm(const void* __restrict__ Xv,
                                            const unsigned short* __restrict__ Wt,
                                            unsigned short* __restrict__ Y) {
    int tid = threadIdx.x;
    int wv = tid >> 6, l = tid & 63;
    int row0 = blockIdx.x * 64 + wv * 16;
    int r = l & 15, kc = l >> 4;
    bf16x8 a[4];
    if (INF32) {
        const float* X = (const float*)Xv;
#pragma unroll
        for (int ks = 0; ks < 4; ++ks) {
            const float* p = X + (long)(row0 + r) * 128 + ks * 32 + kc * 8;
            float4 f0 = *(const float4*)p;
            float4 f1 = *(const float4*)(p + 4);
            bf16x8 t;
            t[0] = (short)f2b(f0.x); t[1] = (short)f2b(f0.y);
            t[2] = (short)f2b(f0.z); t[3] = (short)f2b(f0.w);
            t[4] = (short)f2b(f1.x); t[5] = (short)f2b(f1.y);
            t[6] = (short)f2b(f1.z); t[7] = (short)f2b(f1.w);
            a[ks] = t;
        }
    } else {
        const unsigned short* X = (const unsigned short*)Xv;
#pragma unroll
        for (int ks = 0; ks < 4; ++ks)
            a[ks] = *(const bf16x8*)(X + (long)(row0 + r) * 128 + ks * 32 + kc * 8);
    }
    f32x4 acc[8];
#pragma unroll
    for (int nt = 0; nt < 8; ++nt) acc[nt] = (f32x4){0.f, 0.f, 0.f, 0.f};
#pragma unroll
    for (int ks = 0; ks < 4; ++ks) {
#pragma unroll
        for (int nt = 0; nt < 8; ++nt) {
            bf16x8 b = *(const bf16x8*)(Wt + (nt * 16 + r) * 128 + ks * 32 + kc * 8);
            acc[nt] = __builtin_amdgcn_mfma_f32_16x16x32_bf16(a[ks], b, acc[nt], 0, 0, 0);
        }
    }
#pragma unroll
    for (int nt = 0; nt < 8; ++nt)
#pragma unroll
        for (int j = 0; j < 4; ++j)
            Y[(long)(row0 + kc * 4 + j) * 128 + nt * 16 + r] = f2b(acc[nt][j]);
}

// CSR gather on bf16 features: 1 wave per node, 4B per lane, 4-deep ILP.
// MODE 0: writes out (+bias,relu). MODE 1: NO out write — fused pool:
// block's 4 nodes share one graph; LDS-reduce then atomicAdd into pp[b][c].
template<int MODE>
__global__ __launch_bounds__(256) void k_gather(const unsigned short* __restrict__ feat,
                                                unsigned short* __restrict__ out,
                                                const int* __restrict__ rowptr,
                                                const int* __restrict__ csr_src,
                                                const float* __restrict__ csr_w,
                                                const float* __restrict__ dinv,
                                                const float* __restrict__ bias,
                                                float* __restrict__ pp) {
    __shared__ float sh[4][128];
    int wid = threadIdx.x >> 6, lane = threadIdx.x & 63;
    int v = blockIdx.x * 4 + wid;
    const unsigned int* f2 = (const unsigned int*)feat;
    float dv = dinv[v];
    unsigned int sv = f2[v * 64 + lane];
    float acc0 = b2f((unsigned short)(sv & 0xffff)) * dv * dv;
    float acc1 = b2f((unsigned short)(sv >> 16)) * dv * dv;
    int e = rowptr[v], e1 = rowptr[v + 1];
    for (; e + 4 <= e1; e += 4) {
        int s0 = csr_src[e], s1 = csr_src[e + 1], s2 = csr_src[e + 2], s3 = csr_src[e + 3];
        float w0 = csr_w[e], w1 = csr_w[e + 1], w2 = csr_w[e + 2], w3 = csr_w[e + 3];
        unsigned int u0 = f2[s0 * 64 + lane];
        unsigned int u1 = f2[s1 * 64 + lane];
        unsigned int u2 = f2[s2 * 64 + lane];
        unsigned int u3 = f2[s3 * 64 + lane];
        acc0 += b2f((unsigned short)(u0 & 0xffff)) * w0 + b2f((unsigned short)(u1 & 0xffff)) * w1
              + b2f((unsigned short)(u2 & 0xffff)) * w2 + b2f((unsigned short)(u3 & 0xffff)) * w3;
        acc1 += b2f((unsigned short)(u0 >> 16)) * w0 + b2f((unsigned short)(u1 >> 16)) * w1
              + b2f((unsigned short)(u2 >> 16)) * w2 + b2f((unsigned short)(u3 >> 16)) * w3;
    }
    for (; e < e1; ++e) {
        int s = csr_src[e];
        float w = csr_w[e];
        unsigned int u = f2[s * 64 + lane];
        acc0 += b2f((unsigned short)(u & 0xffff)) * w;
        acc1 += b2f((unsigned short)(u >> 16)) * w;
    }
    if (MODE == 0) {
        int c = lane * 2;
        acc0 = fmaxf(acc0 + bias[c], 0.f);
        acc1 = fmaxf(acc1 + bias[c + 1], 0.f);
        ((unsigned int*)out)[v * 64 + lane] =
            (unsigned int)f2b(acc0) | ((unsigned int)f2b(acc1) << 16);
    } else {
        sh[wid][lane * 2] = acc0;
        sh[wid][lane * 2 + 1] = acc1;
        __syncthreads();
        int tid = threadIdx.x;
        if (tid < 128) {
            int b = (blockIdx.x * 4) / N_PER;   // all 4 nodes same graph (1000%4==0)
            atomicAdd(&pp[b * 128 + tid],
                      sh[0][tid] + sh[1][tid] + sh[2][tid] + sh[3][tid]);
        }
    }
}

// pool stage 2: mean + layer-3 bias from atomic accumulator; writes hg (f32) + hgB (bf16)
__global__ __launch_bounds__(256) void k_pool2(const float* __restrict__ pp,
                                               const float* __restrict__ bias,
                                               float* __restrict__ hg,
                                               unsigned short* __restrict__ hgB) {
    int i = blockIdx.x * 256 + threadIdx.x;
    if (i >= NB * 128) return;
    float v = pp[i] * (1.0f / N_PER) + bias[i & 127];
    hg[i] = v;
    hgB[i] = f2b(v);
}

// k_w1 (MFMA + LDS-coalesced staging + register n-accumulation):
// block = (h, chunk of 4 n); 4 waves. Per n: stage Wg1 column coalescedly into
// LDS bf16 wt[d][k] (rows padded to 136), MFMA, then ACCUMULATE
// softplus(+bg1)*act into 8 per-lane registers across the 4 n's.
// One store per chunk: p1[(h*250+chunk)][b][d]  (6.1 MB total).
__global__ __launch_bounds__(256) void k_w1(const unsigned short* __restrict__ hgB,
                                            const float* __restrict__ Wg1,
                                            const float* __restrict__ bg1,
                                            const float* __restrict__ actions,
                                            float* __restrict__ p1) {
    __shared__ unsigned short wt[64][136];
    int h = blockIdx.x / W1CH, chunk = blockIdx.x % W1CH;
    int tid = threadIdx.x;
    int wv = tid >> 6, l = tid & 63;
    int r = l & 15, kc = l >> 4;
    const long KS = (long)NH * N_PER * Dh;            // 192000
    bf16x8 a[2][4];
#pragma unroll
    for (int mt = 0; mt < 2; ++mt)
#pragma unroll
        for (int ks = 0; ks < 4; ++ks)
            a[mt][ks] = *(const bf16x8*)(hgB + (mt * 16 + r) * 128 + ks * 32 + kc * 8);
    float sp0[4] = {0.f, 0.f, 0.f, 0.f};
    float sp1[4] = {0.f, 0.f, 0.f, 0.f};
    int sd = tid & 63, sk = tid >> 6;
    for (int nn = 0; nn < 4; ++nn) {
        int n = chunk * 4 + nn;
        long colbase = (long)h * (N_PER * Dh) + (long)n * Dh;
        __syncthreads();
        const float* Wb = Wg1 + colbase + sd;
#pragma unroll 8
        for (int it = 0; it < 32; ++it) {
            int k = it * 4 + sk;
            wt[sd][k] = f2b(Wb[(long)k * KS]);
        }
        __syncthreads();
        f32x4 acc0 = (f32x4){0.f, 0.f, 0.f, 0.f};
        f32x4 acc1 = (f32x4){0.f, 0.f, 0.f, 0.f};
#pragma unroll
        for (int ks = 0; ks < 4; ++ks) {
            bf16x8 bb = *(const bf16x8*)&wt[wv * 16 + r][ks * 32 + kc * 8];
            acc0 = __builtin_amdgcn_mfma_f32_16x16x32_bf16(a[0][ks], bb, acc0, 0, 0, 0);
            acc1 = __builtin_amdgcn_mfma_f32_16x16x32_bf16(a[1][ks], bb, acc1, 0, 0, 0);
        }
        float bgv = bg1[colbase + wv * 16 + r];
#pragma unroll
        for (int j = 0; j < 4; ++j) {
            int b0 = kc * 4 + j;
            int b1 = 16 + kc * 4 + j;
            sp0[j] += softplusf(acc0[j] + bgv) * actions[b0 * N_PER + n];
            sp1[j] += softplusf(acc1[j] + bgv) * actions[b1 * N_PER + n];
        }
    }
    float* po = p1 + ((long)h * W1CH + chunk) * 2048;
#pragma unroll
    for (int j = 0; j < 4; ++j) {
        po[(kc * 4 + j) * 64 + wv * 16 + r] = sp0[j];
        po[(16 + kc * 4 + j) * 64 + wv * 16 + r] = sp1[j];
    }
}

// block = (b,h): 96 blocks; thread = (part, d); sums 250 chunk slabs (4-way split)
__global__ __launch_bounds__(256) void k_red1(const float* __restrict__ p1,
                                              float* __restrict__ h1) {
    __shared__ float sh[4][64];
    int b = blockIdx.x / 3, h = blockIdx.x % 3;
    int part = threadIdx.x >> 6, d = threadIdx.x & 63;
    const float* base = p1 + (long)h * W1CH * 2048 + b * 64 + d;
    float s = 0.f;
    for (int ch = part; ch < W1CH; ch += 4)
        s += base[(long)ch * 2048];
    if (part) sh[part][d] = s;
    __syncthreads();
    if (part == 0)
        h1[(b * 3 + h) * 64 + d] = sqrtf(fmaxf(s + sh[1][d] + sh[2][d] + sh[3][d], 0.f) + EPSV);
}

__global__ __launch_bounds__(256) void k_w2(const float* __restrict__ hg,
                                            const float* __restrict__ Wg2,
                                            const float* __restrict__ bg2,
                                            const float* __restrict__ h1,
                                            float* __restrict__ p2) {
    __shared__ float hgs[32][128];
    __shared__ float wt[128][64];
    __shared__ float h1s[32];
    int hd = blockIdx.x;
    int tid = threadIdx.x;
    for (int i = 0; i < 16; ++i) {
        int idx = tid + i * 256;
        hgs[idx >> 7][idx & 127] = hg[idx];
    }
    long base = (long)hd * 64;
    for (int i = 0; i < 32; ++i) {
        int idx = tid + i * 256;
        wt[idx >> 6][idx & 63] = Wg2[(long)(idx >> 6) * (NH * Dh * Dh) + base + (idx & 63)];
    }
    int h = hd >> 6, d = hd & 63;
    if (tid < 32) h1s[tid] = h1[tid * (NH * Dh) + h * Dh + d];
    __syncthreads();
    int e = tid & 63, bq = tid >> 6;
    float bgv = bg2[base + e];
    float dot[8];
#pragma unroll
    for (int bi = 0; bi < 8; ++bi) dot[bi] = 0.f;
    for (int k = 0; k < 128; ++k) {
        float w = wt[k][e];
#pragma unroll
        for (int bi = 0; bi < 8; ++bi)
            dot[bi] += hgs[bq * 8 + bi][k] * w;
    }
    float* po = p2 + (long)hd * (32 * 64);
#pragma unroll
    for (int bi = 0; bi < 8; ++bi) {
        int b = bq * 8 + bi;
        po[b * 64 + e] = softplusf(dot[bi] + bgv) * h1s[b];
    }
}

__global__ __launch_bounds__(256) void k_red2(const float* __restrict__ p2,
                                              float* __restrict__ h2) {
    int o = blockIdx.x * 256 + threadIdx.x;
    if (o >= 32 * 192) return;
    int bh = o >> 6;
    int h = bh % 3, b = bh / 3;
    int e = o & 63;
    float s = 0.f;
    for (int d = 0; d < 64; ++d)
        s += p2[(h * 64 + d) * 2048 + b * 64 + e];
    h2[o] = log1pf(fmaxf(s, 0.f));
}

__global__ __launch_bounds__(192) void k_out(const float* __restrict__ hg,
                                             const float* __restrict__ Wg3,
                                             const float* __restrict__ bg3,
                                             const float* __restrict__ h2,
                                             float* __restrict__ out) {
    __shared__ float hgb[128];
    __shared__ float hres[NH];
    int b = blockIdx.x, tid = threadIdx.x;
    if (tid < 128) hgb[tid] = hg[b * 128 + tid];
    __syncthreads();
    int h = tid / 64, e = tid & 63;
    int c = h * 64 + e;
    float dot = 0.f;
    for (int k = 0; k < 128; ++k)
        dot += hgb[k] * Wg3[k * (NH * Dh) + c];
    float v = softplusf(dot + bg3[c]) * h2[b * 192 + c];
    for (int off = 32; off; off >>= 1)
        v += __shfl_down(v, off, 64);
    if (e == 0) hres[h] = v;
    __syncthreads();
    if (tid == 0) out[b] = fminf(fminf(hres[0], hres[1]), hres[2]);
}

extern "C" void kernel_launch(void* const* d_in, const int* in_sizes, int n_in,
                              void* d_out, int out_size, void* d_ws, size_t ws_size,
                              hipStream_t stream) {
    const float* x   = (const float*)d_in[0];
    const int*   ei  = (const int*)d_in[1];
    const float* act = (const float*)d_in[3];
    const float* Wc1 = (const float*)d_in[4];
    const float* bc1 = (const float*)d_in[5];
    const float* Wc2 = (const float*)d_in[6];
    const float* bc2 = (const float*)d_in[7];
    const float* Wc3 = (const float*)d_in[8];
    const float* bc3 = (const float*)d_in[9];
    const float* Wg1 = (const float*)d_in[10];
    const float* bg1 = (const float*)d_in[11];
    const float* Wg2 = (const float*)d_in[12];
    const float* bg2 = (const float*)d_in[13];
    const float* Wg3 = (const float*)d_in[14];
    const float* bg3 = (const float*)d_in[15];
    float* out = (float*)d_out;

    float* ws   = (float*)d_ws;
    float* dinv = ws;                               // 32000
    float* bufA = dinv + TOTALN;                    // feat A (bf16) / p1,p2 alias
    float* bufB = bufA + (long)TOTALN * 128;        // feat B
    float* hg   = bufB + (long)TOTALN * 128;        // 4096
    float* h1   = hg + 32 * 128;                    // 6144
    float* h2   = h1 + 32 * 192;                    // 6144
    float* csr_w = h2 + 32 * 192;                   // 512000
    float* pp   = csr_w + NE;                       // 4096 (atomic pool accumulator)
    unsigned short* hgB = (unsigned short*)(pp + NB * 128);  // 4096 bf16
    int* cnt    = (int*)(hgB + 4096);               // 32000
    int* rowptr = cnt + TOTALN;                     // 32001 (+3 pad)
    int* cursor = rowptr + TOTALN + 4;              // 32000
    int* bsum   = cursor + TOTALN;                  // 128
    int* csr_src= bsum + 128;                       // 512000
    unsigned short* Wt = (unsigned short*)(csr_src + NE);  // 3*16384 bf16
    unsigned short* fA = (unsigned short*)bufA;
    unsigned short* fB = (unsigned short*)bufB;
    float* p1   = bufA;                             // 3*250*2048 = 1.536M floats
    float* p2   = bufA + (long)NH * W1CH * 2048;    // +393216

    // degree + norm + CSR build (+ zero pool accumulator)
    k_init_deg<<<(TOTALN + 255) / 256, 256, 0, stream>>>(dinv, pp);
    k_deg<<<NE / 256, 256, 0, stream>>>(ei, dinv);
    k_prep<<<(TOTALN + 255) / 256, 256, 0, stream>>>(dinv, cnt);
    k_scan_block<<<125, 256, 0, stream>>>(cnt, rowptr, bsum);
    k_scan_tot<<<1, 64, 0, stream>>>(bsum);
    k_scan_add<<<125, 256, 0, stream>>>(rowptr, bsum, cursor);
    k_fill<<<NE / 256, 256, 0, stream>>>(ei, dinv, cursor, csr_src, csr_w);
    k_wcvt3<<<192, 256, 0, stream>>>(Wc1, Wc2, Wc3, Wt);

    // layer 1 (x f32 -> bf16 MFMA)
    k_mm<1><<<500, 256, 0, stream>>>(x, Wt, fB);
    k_gather<0><<<TOTALN / 4, 256, 0, stream>>>(fB, fA, rowptr, csr_src, csr_w, dinv, bc1, nullptr);
    // layer 2
    k_mm<0><<<500, 256, 0, stream>>>(fA, Wt + 16384, fB);
    k_gather<0><<<TOTALN / 4, 256, 0, stream>>>(fB, fA, rowptr, csr_src, csr_w, dinv, bc2, nullptr);
    // layer 3: gather fused with pooling (no feature write)
    k_mm<0><<<500, 256, 0, stream>>>(fA, Wt + 32768, fB);
    k_gather<1><<<TOTALN / 4, 256, 0, stream>>>(fB, nullptr, rowptr, csr_src, csr_w, dinv, nullptr, pp);
    k_pool2<<<(NB * 128 + 255) / 256, 256, 0, stream>>>(pp, bc3, hg, hgB);

    // hypernetwork + compute_q
    k_w1<<<NH * W1CH, 256, 0, stream>>>(hgB, Wg1, bg1, act, p1);
    k_red1<<<96, 256, 0, stream>>>(p1, h1);
    k_w2<<<NH * Dh, 256, 0, stream>>>(hg, Wg2, bg2, h1, p2);
    k_red2<<<24, 256, 0, stream>>>(p2, h2);
    k_out<<<NB, 192, 0, stream>>>(hg, Wg3, bg3, h2, out);
}

// Round 15
// 279.653 us; speedup vs baseline: 1.0073x; 1.0073x over previous
//
#include <hip/hip_runtime.h>
#include <hip/hip_bf16.h>
#include <math.h>

#define NB 32          // graphs
#define N_PER 1000
#define TOTALN 32000
#define NE 512000
#define HID 128
#define Dh 64
#define NH 3
#define EPSV 1e-6f
#define PCH 25         // pool chunks per graph (40 nodes each)
#define W1CH 250       // k_w1 chunks (4 n's each)

typedef __attribute__((ext_vector_type(8))) short bf16x8;
typedef __attribute__((ext_vector_type(4))) float f32x4;

__device__ __forceinline__ float softplusf(float x) {
    return fmaxf(x, 0.0f) + log1pf(expf(-fabsf(x)));
}
__device__ __forceinline__ unsigned short f2b(float f) {
    __hip_bfloat16 h = __float2bfloat16(f);
    return __builtin_bit_cast(unsigned short, h);
}
__device__ __forceinline__ float b2f(unsigned short u) {
    unsigned int x = ((unsigned int)u) << 16;
    return __builtin_bit_cast(float, x);
}

__global__ __launch_bounds__(256) void k_init_deg(float* deg) {
    int i = blockIdx.x * 256 + threadIdx.x;
    if (i < TOTALN) deg[i] = 1.0f;   // self loop
}

__global__ __launch_bounds__(256) void k_deg(const int* __restrict__ ei, float* deg) {
    int e = blockIdx.x * 256 + threadIdx.x;
    if (e < NE) atomicAdd(&deg[ei[NE + e]], 1.0f);
}

__global__ __launch_bounds__(256) void k_prep(float* __restrict__ d, int* __restrict__ cnt) {
    int i = blockIdx.x * 256 + threadIdx.x;
    if (i < TOTALN) {
        float v = d[i];
        cnt[i] = (int)v - 1;
        d[i] = rsqrtf(v);
    }
}

__global__ __launch_bounds__(256) void k_scan_block(const int* __restrict__ cnt,
                                                    int* __restrict__ rowptr,
                                                    int* __restrict__ bsum) {
    __shared__ int sh[256];
    int t = threadIdx.x;
    int i = blockIdx.x * 256 + t;
    int v = cnt[i];
    sh[t] = v;
    __syncthreads();
    for (int off = 1; off < 256; off <<= 1) {
        int add = (t >= off) ? sh[t - off] : 0;
        __syncthreads();
        sh[t] += add;
        __syncthreads();
    }
    rowptr[i] = sh[t] - v;
    if (t == 255) bsum[blockIdx.x] = sh[255];
}

__global__ void k_scan_tot(int* __restrict__ bsum) {
    if (threadIdx.x == 0) {
        int run = 0;
        for (int i = 0; i < 125; ++i) { int t = bsum[i]; bsum[i] = run; run += t; }
    }
}

__global__ __launch_bounds__(256) void k_scan_add(int* __restrict__ rowptr,
                                                  const int* __restrict__ bsum,
                                                  int* __restrict__ cursor) {
    int i = blockIdx.x * 256 + threadIdx.x;
    int v = rowptr[i] + bsum[blockIdx.x];
    rowptr[i] = v;
    cursor[i] = v;
    if (i == 0) rowptr[TOTALN] = NE;
}

__global__ __launch_bounds__(256) void k_fill(const int* __restrict__ ei,
                                              const float* __restrict__ dinv,
                                              int* __restrict__ cursor,
                                              int* __restrict__ csr_src,
                                              float* __restrict__ csr_w) {
    int e = blockIdx.x * 256 + threadIdx.x;
    if (e < NE) {
        int s = ei[e], d = ei[NE + e];
        int pos = atomicAdd(&cursor[d], 1);
        csr_src[pos] = s;
        csr_w[pos] = dinv[s] * dinv[d];
    }
}

// transpose+convert ALL THREE W[128][128] f32 -> Wt[layer][c][k] bf16 (one launch)
__global__ __launch_bounds__(256) void k_wcvt3(const float* __restrict__ W1,
                                               const float* __restrict__ W2,
                                               const float* __restrict__ W3,
                                               unsigned short* __restrict__ Wt) {
    int i = blockIdx.x * 256 + threadIdx.x;   // 3*16384
    int w = i >> 14, j = i & 16383;
    const float* W = (w == 0) ? W1 : (w == 1) ? W2 : W3;
    int k = j >> 7, c = j & 127;
    Wt[w * 16384 + c * 128 + k] = f2b(W[j]);
}

// Y[32000 x 128](bf16) = X[32000 x 128] @ W ; MFMA 16x16x32 bf16, no LDS.
template<int INF32>
__global__ __launch_bounds__(256) void k_mm(const void* __restrict__ Xv,
                                            const unsigned short* __restrict__ Wt,
                                            unsigned short* __restrict__ Y) {
    int tid = threadIdx.x;
    int wv = tid >> 6, l = tid & 63;
    int row0 = blockIdx.x * 64 + wv * 16;
    int r = l & 15, kc = l >> 4;
    bf16x8 a[4];
    if (INF32) {
        const float* X = (const float*)Xv;
#pragma unroll
        for (int ks = 0; ks < 4; ++ks) {
            const float* p = X + (long)(row0 + r) * 128 + ks * 32 + kc * 8;
            float4 f0 = *(const float4*)p;
            float4 f1 = *(const float4*)(p + 4);
            bf16x8 t;
            t[0] = (short)f2b(f0.x); t[1] = (short)f2b(f0.y);
            t[2] = (short)f2b(f0.z); t[3] = (short)f2b(f0.w);
            t[4] = (short)f2b(f1.x); t[5] = (short)f2b(f1.y);
            t[6] = (short)f2b(f1.z); t[7] = (short)f2b(f1.w);
            a[ks] = t;
        }
    } else {
        const unsigned short* X = (const unsigned short*)Xv;
#pragma unroll
        for (int ks = 0; ks < 4; ++ks)
            a[ks] = *(const bf16x8*)(X + (long)(row0 + r) * 128 + ks * 32 + kc * 8);
    }
    f32x4 acc[8];
#pragma unroll
    for (int nt = 0; nt < 8; ++nt) acc[nt] = (f32x4){0.f, 0.f, 0.f, 0.f};
#pragma unroll
    for (int ks = 0; ks < 4; ++ks) {
#pragma unroll
        for (int nt = 0; nt < 8; ++nt) {
            bf16x8 b = *(const bf16x8*)(Wt + (nt * 16 + r) * 128 + ks * 32 + kc * 8);
            acc[nt] = __builtin_amdgcn_mfma_f32_16x16x32_bf16(a[ks], b, acc[nt], 0, 0, 0);
        }
    }
#pragma unroll
    for (int nt = 0; nt < 8; ++nt)
#pragma unroll
        for (int j = 0; j < 4; ++j)
            Y[(long)(row0 + kc * 4 + j) * 128 + nt * 16 + r] = f2b(acc[nt][j]);
}

// CSR gather on bf16 features: 1 wave per node, 4B per lane, 4-deep ILP.
// MODE 0: +bias,relu ; MODE 1: plain
template<int MODE>
__global__ __launch_bounds__(256) void k_gather(const unsigned short* __restrict__ feat,
                                                unsigned short* __restrict__ out,
                                                const int* __restrict__ rowptr,
                                                const int* __restrict__ csr_src,
                                                const float* __restrict__ csr_w,
                                                const float* __restrict__ dinv,
                                                const float* __restrict__ bias) {
    int wid = threadIdx.x >> 6, lane = threadIdx.x & 63;
    int v = blockIdx.x * 4 + wid;
    const unsigned int* f2 = (const unsigned int*)feat;
    float dv = dinv[v];
    unsigned int sv = f2[v * 64 + lane];
    float acc0 = b2f((unsigned short)(sv & 0xffff)) * dv * dv;
    float acc1 = b2f((unsigned short)(sv >> 16)) * dv * dv;
    int e = rowptr[v], e1 = rowptr[v + 1];
    for (; e + 4 <= e1; e += 4) {
        int s0 = csr_src[e], s1 = csr_src[e + 1], s2 = csr_src[e + 2], s3 = csr_src[e + 3];
        float w0 = csr_w[e], w1 = csr_w[e + 1], w2 = csr_w[e + 2], w3 = csr_w[e + 3];
        unsigned int u0 = f2[s0 * 64 + lane];
        unsigned int u1 = f2[s1 * 64 + lane];
        unsigned int u2 = f2[s2 * 64 + lane];
        unsigned int u3 = f2[s3 * 64 + lane];
        acc0 += b2f((unsigned short)(u0 & 0xffff)) * w0 + b2f((unsigned short)(u1 & 0xffff)) * w1
              + b2f((unsigned short)(u2 & 0xffff)) * w2 + b2f((unsigned short)(u3 & 0xffff)) * w3;
        acc1 += b2f((unsigned short)(u0 >> 16)) * w0 + b2f((unsigned short)(u1 >> 16)) * w1
              + b2f((unsigned short)(u2 >> 16)) * w2 + b2f((unsigned short)(u3 >> 16)) * w3;
    }
    for (; e < e1; ++e) {
        int s = csr_src[e];
        float w = csr_w[e];
        unsigned int u = f2[s * 64 + lane];
        acc0 += b2f((unsigned short)(u & 0xffff)) * w;
        acc1 += b2f((unsigned short)(u >> 16)) * w;
    }
    if (MODE == 0) {
        int c = lane * 2;
        acc0 = fmaxf(acc0 + bias[c], 0.f);
        acc1 = fmaxf(acc1 + bias[c + 1], 0.f);
    }
    ((unsigned int*)out)[v * 64 + lane] =
        (unsigned int)f2b(acc0) | ((unsigned int)f2b(acc1) << 16);
}

// pool stage 1 (bf16 input)
__global__ __launch_bounds__(256) void k_pool1(const unsigned short* __restrict__ A,
                                               float* __restrict__ pp) {
    __shared__ float sh[256];
    int b = blockIdx.x / PCH, ch = blockIdx.x % PCH;
    int c = threadIdx.x & 127, half = threadIdx.x >> 7;
    float acc = 0.f;
    int n0 = ch * 40;
#pragma unroll 4
    for (int j = half; j < 40; j += 2)
        acc += b2f(A[(long)(b * N_PER + n0 + j) * 128 + c]);
    sh[threadIdx.x] = acc;
    __syncthreads();
    if (threadIdx.x < 128)
        pp[blockIdx.x * 128 + c] = sh[c] + sh[128 + c];
}

// pool stage 2: reduce 25 partials, mean + layer-3 bias; writes hg (f32) + hgB (bf16)
__global__ __launch_bounds__(256) void k_pool2(const float* __restrict__ pp,
                                               const float* __restrict__ bias,
                                               float* __restrict__ hg,
                                               unsigned short* __restrict__ hgB) {
    int i = blockIdx.x * 256 + threadIdx.x;
    if (i >= NB * 128) return;
    int b = i >> 7, c = i & 127;
    float s = 0.f;
#pragma unroll
    for (int ch = 0; ch < PCH; ++ch)
        s += pp[(b * PCH + ch) * 128 + c];
    float v = s * (1.0f / N_PER) + bias[c];
    hg[i] = v;
    hgB[i] = f2b(v);
}

// k_w1 (MFMA + LDS-coalesced staging + register n-accumulation):
// block = (h, chunk of 4 n); 4 waves. Per n: stage Wg1 column coalescedly into
// LDS bf16 wt[d][k] (rows padded to 136), MFMA, ACCUMULATE softplus(+bg1)*act
// into 8 registers across the 4 n's; one store per chunk (6.1 MB p1).
__global__ __launch_bounds__(256) void k_w1(const unsigned short* __restrict__ hgB,
                                            const float* __restrict__ Wg1,
                                            const float* __restrict__ bg1,
                                            const float* __restrict__ actions,
                                            float* __restrict__ p1) {
    __shared__ unsigned short wt[64][136];
    int h = blockIdx.x / W1CH, chunk = blockIdx.x % W1CH;
    int tid = threadIdx.x;
    int wv = tid >> 6, l = tid & 63;
    int r = l & 15, kc = l >> 4;
    const long KS = (long)NH * N_PER * Dh;            // 192000
    bf16x8 a[2][4];
#pragma unroll
    for (int mt = 0; mt < 2; ++mt)
#pragma unroll
        for (int ks = 0; ks < 4; ++ks)
            a[mt][ks] = *(const bf16x8*)(hgB + (mt * 16 + r) * 128 + ks * 32 + kc * 8);
    float sp0[4] = {0.f, 0.f, 0.f, 0.f};
    float sp1[4] = {0.f, 0.f, 0.f, 0.f};
    int sd = tid & 63, sk = tid >> 6;
    for (int nn = 0; nn < 4; ++nn) {
        int n = chunk * 4 + nn;
        long colbase = (long)h * (N_PER * Dh) + (long)n * Dh;
        __syncthreads();
        const float* Wb = Wg1 + colbase + sd;
#pragma unroll 8
        for (int it = 0; it < 32; ++it) {
            int k = it * 4 + sk;
            wt[sd][k] = f2b(Wb[(long)k * KS]);
        }
        __syncthreads();
        f32x4 acc0 = (f32x4){0.f, 0.f, 0.f, 0.f};
        f32x4 acc1 = (f32x4){0.f, 0.f, 0.f, 0.f};
#pragma unroll
        for (int ks = 0; ks < 4; ++ks) {
            bf16x8 bb = *(const bf16x8*)&wt[wv * 16 + r][ks * 32 + kc * 8];
            acc0 = __builtin_amdgcn_mfma_f32_16x16x32_bf16(a[0][ks], bb, acc0, 0, 0, 0);
            acc1 = __builtin_amdgcn_mfma_f32_16x16x32_bf16(a[1][ks], bb, acc1, 0, 0, 0);
        }
        float bgv = bg1[colbase + wv * 16 + r];
#pragma unroll
        for (int j = 0; j < 4; ++j) {
            int b0 = kc * 4 + j;
            int b1 = 16 + kc * 4 + j;
            sp0[j] += softplusf(acc0[j] + bgv) * actions[b0 * N_PER + n];
            sp1[j] += softplusf(acc1[j] + bgv) * actions[b1 * N_PER + n];
        }
    }
    float* po = p1 + ((long)h * W1CH + chunk) * 2048;
#pragma unroll
    for (int j = 0; j < 4; ++j) {
        po[(kc * 4 + j) * 64 + wv * 16 + r] = sp0[j];
        po[(16 + kc * 4 + j) * 64 + wv * 16 + r] = sp1[j];
    }
}

// block = (b,h): 96 blocks; thread = (part, d); sums 250 chunk slabs (4-way split)
__global__ __launch_bounds__(256) void k_red1(const float* __restrict__ p1,
                                              float* __restrict__ h1) {
    __shared__ float sh[4][64];
    int b = blockIdx.x / 3, h = blockIdx.x % 3;
    int part = threadIdx.x >> 6, d = threadIdx.x & 63;
    const float* base = p1 + (long)h * W1CH * 2048 + b * 64 + d;
    float s = 0.f;
    for (int ch = part; ch < W1CH; ch += 4)
        s += base[(long)ch * 2048];
    if (part) sh[part][d] = s;
    __syncthreads();
    if (part == 0)
        h1[(b * 3 + h) * 64 + d] = sqrtf(fmaxf(s + sh[1][d] + sh[2][d] + sh[3][d], 0.f) + EPSV);
}

__global__ __launch_bounds__(256) void k_w2(const float* __restrict__ hg,
                                            const float* __restrict__ Wg2,
                                            const float* __restrict__ bg2,
                                            const float* __restrict__ h1,
                                            float* __restrict__ p2) {
    __shared__ float hgs[32][128];
    __shared__ float wt[128][64];
    __shared__ float h1s[32];
    int hd = blockIdx.x;
    int tid = threadIdx.x;
    for (int i = 0; i < 16; ++i) {
        int idx = tid + i * 256;
        hgs[idx >> 7][idx & 127] = hg[idx];
    }
    long base = (long)hd * 64;
    for (int i = 0; i < 32; ++i) {
        int idx = tid + i * 256;
        wt[idx >> 6][idx & 63] = Wg2[(long)(idx >> 6) * (NH * Dh * Dh) + base + (idx & 63)];
    }
    int h = hd >> 6, d = hd & 63;
    if (tid < 32) h1s[tid] = h1[tid * (NH * Dh) + h * Dh + d];
    __syncthreads();
    int e = tid & 63, bq = tid >> 6;
    float bgv = bg2[base + e];
    float dot[8];
#pragma unroll
    for (int bi = 0; bi < 8; ++bi) dot[bi] = 0.f;
    for (int k = 0; k < 128; ++k) {
        float w = wt[k][e];
#pragma unroll
        for (int bi = 0; bi < 8; ++bi)
            dot[bi] += hgs[bq * 8 + bi][k] * w;
    }
    float* po = p2 + (long)hd * (32 * 64);
#pragma unroll
    for (int bi = 0; bi < 8; ++bi) {
        int b = bq * 8 + bi;
        po[b * 64 + e] = softplusf(dot[bi] + bgv) * h1s[b];
    }
}

__global__ __launch_bounds__(256) void k_red2(const float* __restrict__ p2,
                                              float* __restrict__ h2) {
    int o = blockIdx.x * 256 + threadIdx.x;
    if (o >= 32 * 192) return;
    int bh = o >> 6;
    int h = bh % 3, b = bh / 3;
    int e = o & 63;
    float s = 0.f;
    for (int d = 0; d < 64; ++d)
        s += p2[(h * 64 + d) * 2048 + b * 64 + e];
    h2[o] = log1pf(fmaxf(s, 0.f));
}

__global__ __launch_bounds__(192) void k_out(const float* __restrict__ hg,
                                             const float* __restrict__ Wg3,
                                             const float* __restrict__ bg3,
                                             const float* __restrict__ h2,
                                             float* __restrict__ out) {
    __shared__ float hgb[128];
    __shared__ float hres[NH];
    int b = blockIdx.x, tid = threadIdx.x;
    if (tid < 128) hgb[tid] = hg[b * 128 + tid];
    __syncthreads();
    int h = tid / 64, e = tid & 63;
    int c = h * 64 + e;
    float dot = 0.f;
    for (int k = 0; k < 128; ++k)
        dot += hgb[k] * Wg3[k * (NH * Dh) + c];
    float v = softplusf(dot + bg3[c]) * h2[b * 192 + c];
    for (int off = 32; off; off >>= 1)
        v += __shfl_down(v, off, 64);
    if (e == 0) hres[h] = v;
    __syncthreads();
    if (tid == 0) out[b] = fminf(fminf(hres[0], hres[1]), hres[2]);
}

extern "C" void kernel_launch(void* const* d_in, const int* in_sizes, int n_in,
                              void* d_out, int out_size, void* d_ws, size_t ws_size,
                              hipStream_t stream) {
    const float* x   = (const float*)d_in[0];
    const int*   ei  = (const int*)d_in[1];
    const float* act = (const float*)d_in[3];
    const float* Wc1 = (const float*)d_in[4];
    const float* bc1 = (const float*)d_in[5];
    const float* Wc2 = (const float*)d_in[6];
    const float* bc2 = (const float*)d_in[7];
    const float* Wc3 = (const float*)d_in[8];
    const float* bc3 = (const float*)d_in[9];
    const float* Wg1 = (const float*)d_in[10];
    const float* bg1 = (const float*)d_in[11];
    const float* Wg2 = (const float*)d_in[12];
    const float* bg2 = (const float*)d_in[13];
    const float* Wg3 = (const float*)d_in[14];
    const float* bg3 = (const float*)d_in[15];
    float* out = (float*)d_out;

    float* ws   = (float*)d_ws;
    float* dinv = ws;                               // 32000
    float* bufA = dinv + TOTALN;                    // feat A (bf16) / p1,p2 alias
    float* bufB = bufA + (long)TOTALN * 128;        // feat B
    float* hg   = bufB + (long)TOTALN * 128;        // 4096
    float* h1   = hg + 32 * 128;                    // 6144
    float* h2   = h1 + 32 * 192;                    // 6144
    float* csr_w = h2 + 32 * 192;                   // 512000
    float* pp   = csr_w + NE;                       // 102400 (pool partials)
    unsigned short* hgB = (unsigned short*)(pp + NB * PCH * 128);  // 4096 bf16
    int* cnt    = (int*)(hgB + 4096);               // 32000
    int* rowptr = cnt + TOTALN;                     // 32001 (+3 pad)
    int* cursor = rowptr + TOTALN + 4;              // 32000
    int* bsum   = cursor + TOTALN;                  // 128
    int* csr_src= bsum + 128;                       // 512000
    unsigned short* Wt = (unsigned short*)(csr_src + NE);  // 3*16384 bf16
    unsigned short* fA = (unsigned short*)bufA;
    unsigned short* fB = (unsigned short*)bufB;
    float* p1   = bufA;                             // 3*250*2048 = 1.536M floats
    float* p2   = bufA + (long)NH * W1CH * 2048;    // +393216

    // degree + norm + CSR build
    k_init_deg<<<(TOTALN + 255) / 256, 256, 0, stream>>>(dinv);
    k_deg<<<NE / 256, 256, 0, stream>>>(ei, dinv);
    k_prep<<<(TOTALN + 255) / 256, 256, 0, stream>>>(dinv, cnt);
    k_scan_block<<<125, 256, 0, stream>>>(cnt, rowptr, bsum);
    k_scan_tot<<<1, 64, 0, stream>>>(bsum);
    k_scan_add<<<125, 256, 0, stream>>>(rowptr, bsum, cursor);
    k_fill<<<NE / 256, 256, 0, stream>>>(ei, dinv, cursor, csr_src, csr_w);
    k_wcvt3<<<192, 256, 0, stream>>>(Wc1, Wc2, Wc3, Wt);

    // layer 1 (x f32 -> bf16 MFMA)
    k_mm<1><<<500, 256, 0, stream>>>(x, Wt, fB);
    k_gather<0><<<TOTALN / 4, 256, 0, stream>>>(fB, fA, rowptr, csr_src, csr_w, dinv, bc1);
    // layer 2
    k_mm<0><<<500, 256, 0, stream>>>(fA, Wt + 16384, fB);
    k_gather<0><<<TOTALN / 4, 256, 0, stream>>>(fB, fA, rowptr, csr_src, csr_w, dinv, bc2);
    // layer 3 (no relu; bias folded into pool stage 2)
    k_mm<0><<<500, 256, 0, stream>>>(fA, Wt + 32768, fB);
    k_gather<1><<<TOTALN / 4, 256, 0, stream>>>(fB, fA, rowptr, csr_src, csr_w, dinv, nullptr);
    k_pool1<<<NB * PCH, 256, 0, stream>>>(fA, pp);
    k_pool2<<<(NB * 128 + 255) / 256, 256, 0, stream>>>(pp, bc3, hg, hgB);

    // hypernetwork + compute_q
    k_w1<<<NH * W1CH, 256, 0, stream>>>(hgB, Wg1, bg1, act, p1);
    k_red1<<<96, 256, 0, stream>>>(p1, h1);
    k_w2<<<NH * Dh, 256, 0, stream>>>(hg, Wg2, bg2, h1, p2);
    k_red2<<<24, 256, 0, stream>>>(p2, h2);
    k_out<<<NB, 192, 0, stream>>>(hg, Wg3, bg3, h2, out);
}

// Round 16
// 269.544 us; speedup vs baseline: 1.0451x; 1.0375x over previous
//
#include <hip/hip_runtime.h>
#include <hip/hip_bf16.h>
#include <math.h>

#define NB 32          // graphs
#define N_PER 1000
#define TOTALN 32000
#define NE 512000
#define HID 128
#define Dh 64
#define NH 3
#define EPSV 1e-6f
#define PCH 25         // pool chunks per graph (40 nodes each)
#define W1CH 500       // k_w1 chunks (2 n's each)

typedef __attribute__((ext_vector_type(8))) short bf16x8;
typedef __attribute__((ext_vector_type(4))) float f32x4;

__device__ __forceinline__ float softplusf(float x) {
    return fmaxf(x, 0.0f) + log1pf(expf(-fabsf(x)));
}
__device__ __forceinline__ unsigned short f2b(float f) {
    __hip_bfloat16 h = __float2bfloat16(f);
    return __builtin_bit_cast(unsigned short, h);
}
__device__ __forceinline__ float b2f(unsigned short u) {
    unsigned int x = ((unsigned int)u) << 16;
    return __builtin_bit_cast(float, x);
}

__global__ __launch_bounds__(256) void k_init_deg(float* deg) {
    int i = blockIdx.x * 256 + threadIdx.x;
    if (i < TOTALN) deg[i] = 1.0f;   // self loop
}

__global__ __launch_bounds__(256) void k_deg(const int* __restrict__ ei, float* deg) {
    int e = blockIdx.x * 256 + threadIdx.x;
    if (e < NE) atomicAdd(&deg[ei[NE + e]], 1.0f);
}

__global__ __launch_bounds__(256) void k_prep(float* __restrict__ d, int* __restrict__ cnt) {
    int i = blockIdx.x * 256 + threadIdx.x;
    if (i < TOTALN) {
        float v = d[i];
        cnt[i] = (int)v - 1;
        d[i] = rsqrtf(v);
    }
}

__global__ __launch_bounds__(256) void k_scan_block(const int* __restrict__ cnt,
                                                    int* __restrict__ rowptr,
                                                    int* __restrict__ bsum) {
    __shared__ int sh[256];
    int t = threadIdx.x;
    int i = blockIdx.x * 256 + t;
    int v = cnt[i];
    sh[t] = v;
    __syncthreads();
    for (int off = 1; off < 256; off <<= 1) {
        int add = (t >= off) ? sh[t - off] : 0;
        __syncthreads();
        sh[t] += add;
        __syncthreads();
    }
    rowptr[i] = sh[t] - v;
    if (t == 255) bsum[blockIdx.x] = sh[255];
}

__global__ void k_scan_tot(int* __restrict__ bsum) {
    if (threadIdx.x == 0) {
        int run = 0;
        for (int i = 0; i < 125; ++i) { int t = bsum[i]; bsum[i] = run; run += t; }
    }
}

__global__ __launch_bounds__(256) void k_scan_add(int* __restrict__ rowptr,
                                                  const int* __restrict__ bsum,
                                                  int* __restrict__ cursor) {
    int i = blockIdx.x * 256 + threadIdx.x;
    int v = rowptr[i] + bsum[blockIdx.x];
    rowptr[i] = v;
    cursor[i] = v;
    if (i == 0) rowptr[TOTALN] = NE;
}

__global__ __launch_bounds__(256) void k_fill(const int* __restrict__ ei,
                                              const float* __restrict__ dinv,
                                              int* __restrict__ cursor,
                                              int* __restrict__ csr_src,
                                              float* __restrict__ csr_w) {
    int e = blockIdx.x * 256 + threadIdx.x;
    if (e < NE) {
        int s = ei[e], d = ei[NE + e];
        int pos = atomicAdd(&cursor[d], 1);
        csr_src[pos] = s;
        csr_w[pos] = dinv[s] * dinv[d];
    }
}

// transpose+convert W[128][128] f32 -> Wt[c][k] bf16
__global__ __launch_bounds__(256) void k_wcvt(const float* __restrict__ W,
                                              unsigned short* __restrict__ Wt) {
    int i = blockIdx.x * 256 + threadIdx.x;   // 16384
    int k = i >> 7, c = i & 127;
    Wt[c * 128 + k] = f2b(W[i]);
}

// Y[32000 x 128](bf16) = X[32000 x 128] @ W ; MFMA 16x16x32 bf16, no LDS.
template<int INF32>
__global__ __launch_bounds__(256) void k_mm(const void* __restrict__ Xv,
                                            const unsigned short* __restrict__ Wt,
                                            unsigned short* __restrict__ Y) {
    int tid = threadIdx.x;
    int wv = tid >> 6, l = tid & 63;
    int row0 = blockIdx.x * 64 + wv * 16;
    int r = l & 15, kc = l >> 4;
    bf16x8 a[4];
    if (INF32) {
        const float* X = (const float*)Xv;
#pragma unroll
        for (int ks = 0; ks < 4; ++ks) {
            const float* p = X + (long)(row0 + r) * 128 + ks * 32 + kc * 8;
            float4 f0 = *(const float4*)p;
            float4 f1 = *(const float4*)(p + 4);
            bf16x8 t;
            t[0] = (short)f2b(f0.x); t[1] = (short)f2b(f0.y);
            t[2] = (short)f2b(f0.z); t[3] = (short)f2b(f0.w);
            t[4] = (short)f2b(f1.x); t[5] = (short)f2b(f1.y);
            t[6] = (short)f2b(f1.z); t[7] = (short)f2b(f1.w);
            a[ks] = t;
        }
    } else {
        const unsigned short* X = (const unsigned short*)Xv;
#pragma unroll
        for (int ks = 0; ks < 4; ++ks)
            a[ks] = *(const bf16x8*)(X + (long)(row0 + r) * 128 + ks * 32 + kc * 8);
    }
    f32x4 acc[8];
#pragma unroll
    for (int nt = 0; nt < 8; ++nt) acc[nt] = (f32x4){0.f, 0.f, 0.f, 0.f};
#pragma unroll
    for (int ks = 0; ks < 4; ++ks) {
#pragma unroll
        for (int nt = 0; nt < 8; ++nt) {
            bf16x8 b = *(const bf16x8*)(Wt + (nt * 16 + r) * 128 + ks * 32 + kc * 8);
            acc[nt] = __builtin_amdgcn_mfma_f32_16x16x32_bf16(a[ks], b, acc[nt], 0, 0, 0);
        }
    }
#pragma unroll
    for (int nt = 0; nt < 8; ++nt)
#pragma unroll
        for (int j = 0; j < 4; ++j)
            Y[(long)(row0 + kc * 4 + j) * 128 + nt * 16 + r] = f2b(acc[nt][j]);
}

// CSR gather on bf16 features: 1 wave per node, 4B per lane, 4-deep ILP.
// MODE 0: +bias,relu ; MODE 1: plain
template<int MODE>
__global__ __launch_bounds__(256) void k_gather(const unsigned short* __restrict__ feat,
                                                unsigned short* __restrict__ out,
                                                const int* __restrict__ rowptr,
                                                const int* __restrict__ csr_src,
                                                const float* __restrict__ csr_w,
                                                const float* __restrict__ dinv,
                                                const float* __restrict__ bias) {
    int wid = threadIdx.x >> 6, lane = threadIdx.x & 63;
    int v = blockIdx.x * 4 + wid;
    const unsigned int* f2 = (const unsigned int*)feat;
    float dv = dinv[v];
    unsigned int sv = f2[v * 64 + lane];
    float acc0 = b2f((unsigned short)(sv & 0xffff)) * dv * dv;
    float acc1 = b2f((unsigned short)(sv >> 16)) * dv * dv;
    int e = rowptr[v], e1 = rowptr[v + 1];
    for (; e + 4 <= e1; e += 4) {
        int s0 = csr_src[e], s1 = csr_src[e + 1], s2 = csr_src[e + 2], s3 = csr_src[e + 3];
        float w0 = csr_w[e], w1 = csr_w[e + 1], w2 = csr_w[e + 2], w3 = csr_w[e + 3];
        unsigned int u0 = f2[s0 * 64 + lane];
        unsigned int u1 = f2[s1 * 64 + lane];
        unsigned int u2 = f2[s2 * 64 + lane];
        unsigned int u3 = f2[s3 * 64 + lane];
        acc0 += b2f((unsigned short)(u0 & 0xffff)) * w0 + b2f((unsigned short)(u1 & 0xffff)) * w1
              + b2f((unsigned short)(u2 & 0xffff)) * w2 + b2f((unsigned short)(u3 & 0xffff)) * w3;
        acc1 += b2f((unsigned short)(u0 >> 16)) * w0 + b2f((unsigned short)(u1 >> 16)) * w1
              + b2f((unsigned short)(u2 >> 16)) * w2 + b2f((unsigned short)(u3 >> 16)) * w3;
    }
    for (; e < e1; ++e) {
        int s = csr_src[e];
        float w = csr_w[e];
        unsigned int u = f2[s * 64 + lane];
        acc0 += b2f((unsigned short)(u & 0xffff)) * w;
        acc1 += b2f((unsigned short)(u >> 16)) * w;
    }
    if (MODE == 0) {
        int c = lane * 2;
        acc0 = fmaxf(acc0 + bias[c], 0.f);
        acc1 = fmaxf(acc1 + bias[c + 1], 0.f);
    }
    ((unsigned int*)out)[v * 64 + lane] =
        (unsigned int)f2b(acc0) | ((unsigned int)f2b(acc1) << 16);
}

// pool stage 1 (bf16 input)
__global__ __launch_bounds__(256) void k_pool1(const unsigned short* __restrict__ A,
                                               float* __restrict__ pp) {
    __shared__ float sh[256];
    int b = blockIdx.x / PCH, ch = blockIdx.x % PCH;
    int c = threadIdx.x & 127, half = threadIdx.x >> 7;
    float acc = 0.f;
    int n0 = ch * 40;
#pragma unroll 4
    for (int j = half; j < 40; j += 2)
        acc += b2f(A[(long)(b * N_PER + n0 + j) * 128 + c]);
    sh[threadIdx.x] = acc;
    __syncthreads();
    if (threadIdx.x < 128)
        pp[blockIdx.x * 128 + c] = sh[c] + sh[128 + c];
}

// pool stage 2: mean + layer-3 bias; writes hg (f32), hgT (f32) and hgB (bf16)
__global__ __launch_bounds__(256) void k_pool2(const float* __restrict__ pp,
                                               const float* __restrict__ bias,
                                               float* __restrict__ hg,
                                               float* __restrict__ hgT,
                                               unsigned short* __restrict__ hgB) {
    int i = blockIdx.x * 256 + threadIdx.x;
    if (i >= NB * 128) return;
    int b = i >> 7, c = i & 127;
    float s = 0.f;
#pragma unroll
    for (int ch = 0; ch < PCH; ++ch)
        s += pp[(b * PCH + ch) * 128 + c];
    float v = s * (1.0f / N_PER) + bias[c];
    hg[i] = v;
    hgT[c * NB + b] = v;
    hgB[i] = f2b(v);
}

// k_w1 (MFMA + LDS-coalesced staging): block = (h, chunk of 2 n); 4 waves.
// Per n: stage Wg1 column [128k x 64d] COALESCED (256B d-rows) into LDS as
// bf16 wt[d][k] (rows padded to 136), then each wave computes its 16-d slice.
// 1500 blocks (vs R13's 750) — pure occupancy lever, same total traffic.
// Epilogue softplus(+bg1)*act -> per-n slab p1[(h,n)][b][d]; red1a/b sum n.
__global__ __launch_bounds__(256) void k_w1(const unsigned short* __restrict__ hgB,
                                            const float* __restrict__ Wg1,
                                            const float* __restrict__ bg1,
                                            const float* __restrict__ actions,
                                            float* __restrict__ p1) {
    __shared__ unsigned short wt[64][136];   // [d][k], pad 128->136 (16B-aligned rows)
    int h = blockIdx.x / W1CH, chunk = blockIdx.x % W1CH;
    int tid = threadIdx.x;
    int wv = tid >> 6, l = tid & 63;
    int r = l & 15, kc = l >> 4;
    const long KS = (long)NH * N_PER * Dh;            // 192000
    bf16x8 a[2][4];
#pragma unroll
    for (int mt = 0; mt < 2; ++mt)
#pragma unroll
        for (int ks = 0; ks < 4; ++ks)
            a[mt][ks] = *(const bf16x8*)(hgB + (mt * 16 + r) * 128 + ks * 32 + kc * 8);
    int sd = tid & 63, sk = tid >> 6;   // staging: (d=sd, k = it*4+sk)
    for (int nn = 0; nn < 2; ++nn) {
        int n = chunk * 2 + nn;
        long colbase = (long)h * (N_PER * Dh) + (long)n * Dh;
        __syncthreads();   // previous compute done before overwrite
        const float* Wb = Wg1 + colbase + sd;
#pragma unroll 8
        for (int it = 0; it < 32; ++it) {
            int k = it * 4 + sk;
            wt[sd][k] = f2b(Wb[(long)k * KS]);   // global read coalesced along d
        }
        __syncthreads();
        f32x4 acc0 = (f32x4){0.f, 0.f, 0.f, 0.f};
        f32x4 acc1 = (f32x4){0.f, 0.f, 0.f, 0.f};
#pragma unroll
        for (int ks = 0; ks < 4; ++ks) {
            bf16x8 bb = *(const bf16x8*)&wt[wv * 16 + r][ks * 32 + kc * 8];
            acc0 = __builtin_amdgcn_mfma_f32_16x16x32_bf16(a[0][ks], bb, acc0, 0, 0, 0);
            acc1 = __builtin_amdgcn_mfma_f32_16x16x32_bf16(a[1][ks], bb, acc1, 0, 0, 0);
        }
        // epilogue: wave wv owns cols d = wv*16 + r
        float bgv = bg1[colbase + wv * 16 + r];
        float* po = p1 + ((long)h * N_PER + n) * 2048;
#pragma unroll
        for (int j = 0; j < 4; ++j) {
            int b0 = kc * 4 + j;
            int b1 = 16 + kc * 4 + j;
            po[b0 * 64 + wv * 16 + r] = softplusf(acc0[j] + bgv) * actions[b0 * N_PER + n];
            po[b1 * 64 + wv * 16 + r] = softplusf(acc1[j] + bgv) * actions[b1 * N_PER + n];
        }
    }
}

// red1 stage A: grid 96*8; block = (bh, seg of 125 n); 4 part x 64 d
__global__ __launch_bounds__(256) void k_red1a(const float* __restrict__ p1,
                                               float* __restrict__ rp) {
    __shared__ float sh[4][64];
    int bh = blockIdx.x >> 3, seg = blockIdx.x & 7;   // bh = b*3+h
    int b = bh / 3, h = bh % 3;
    int part = threadIdx.x >> 6, d = threadIdx.x & 63;
    const float* base = p1 + (long)h * N_PER * 2048 + b * 64 + d;
    float s = 0.f;
    for (int n = seg * 125 + part; n < seg * 125 + 125; n += 4)
        s += base[(long)n * 2048];
    if (part) sh[part][d] = s;
    __syncthreads();
    if (part == 0)
        rp[((long)bh * 8 + seg) * 64 + d] = s + sh[1][d] + sh[2][d] + sh[3][d];
}

// red1 stage B: 96*64 outputs; sum 8 segs + SafeSqrt
__global__ __launch_bounds__(256) void k_red1b(const float* __restrict__ rp,
                                               float* __restrict__ h1) {
    int o = blockIdx.x * 256 + threadIdx.x;
    if (o >= 96 * 64) return;
    int bh = o >> 6, d = o & 63;
    float s = 0.f;
#pragma unroll
    for (int seg = 0; seg < 8; ++seg)
        s += rp[((long)bh * 8 + seg) * 64 + d];
    h1[bh * 64 + d] = sqrtf(fmaxf(s, 0.f) + EPSV);
}

__global__ __launch_bounds__(256) void k_w2(const float* __restrict__ hg,
                                            const float* __restrict__ Wg2,
                                            const float* __restrict__ bg2,
                                            const float* __restrict__ h1,
                                            float* __restrict__ p2) {
    __shared__ float hgs[32][128];
    __shared__ float wt[128][64];
    __shared__ float h1s[32];
    int hd = blockIdx.x;
    int tid = threadIdx.x;
    for (int i = 0; i < 16; ++i) {
        int idx = tid + i * 256;
        hgs[idx >> 7][idx & 127] = hg[idx];
    }
    long base = (long)hd * 64;
    for (int i = 0; i < 32; ++i) {
        int idx = tid + i * 256;
        wt[idx >> 6][idx & 63] = Wg2[(long)(idx >> 6) * (NH * Dh * Dh) + base + (idx & 63)];
    }
    int h = hd >> 6, d = hd & 63;
    if (tid < 32) h1s[tid] = h1[tid * (NH * Dh) + h * Dh + d];
    __syncthreads();
    int e = tid & 63, bq = tid >> 6;
    float bgv = bg2[base + e];
    float dot[8];
#pragma unroll
    for (int bi = 0; bi < 8; ++bi) dot[bi] = 0.f;
    for (int k = 0; k < 128; ++k) {
        float w = wt[k][e];
#pragma unroll
        for (int bi = 0; bi < 8; ++bi)
            dot[bi] += hgs[bq * 8 + bi][k] * w;
    }
    float* po = p2 + (long)hd * (32 * 64);
#pragma unroll
    for (int bi = 0; bi < 8; ++bi) {
        int b = bq * 8 + bi;
        po[b * 64 + e] = softplusf(dot[bi] + bgv) * h1s[b];
    }
}

__global__ __launch_bounds__(256) void k_red2(const float* __restrict__ p2,
                                              float* __restrict__ h2) {
    int o = blockIdx.x * 256 + threadIdx.x;
    if (o >= 32 * 192) return;
    int bh = o >> 6;
    int h = bh % 3, b = bh / 3;
    int e = o & 63;
    float s = 0.f;
    for (int d = 0; d < 64; ++d)
        s += p2[(h * 64 + d) * 2048 + b * 64 + e];
    h2[o] = log1pf(fmaxf(s, 0.f));
}

__global__ __launch_bounds__(192) void k_out(const float* __restrict__ hg,
                                             const float* __restrict__ Wg3,
                                             const float* __restrict__ bg3,
                                             const float* __restrict__ h2,
                                             float* __restrict__ out) {
    __shared__ float hgb[128];
    __shared__ float hres[NH];
    int b = blockIdx.x, tid = threadIdx.x;
    if (tid < 128) hgb[tid] = hg[b * 128 + tid];
    __syncthreads();
    int h = tid / 64, e = tid & 63;
    int c = h * 64 + e;
    float dot = 0.f;
    for (int k = 0; k < 128; ++k)
        dot += hgb[k] * Wg3[k * (NH * Dh) + c];
    float v = softplusf(dot + bg3[c]) * h2[b * 192 + c];
    for (int off = 32; off; off >>= 1)
        v += __shfl_down(v, off, 64);
    if (e == 0) hres[h] = v;
    __syncthreads();
    if (tid == 0) out[b] = fminf(fminf(hres[0], hres[1]), hres[2]);
}

extern "C" void kernel_launch(void* const* d_in, const int* in_sizes, int n_in,
                              void* d_out, int out_size, void* d_ws, size_t ws_size,
                              hipStream_t stream) {
    const float* x   = (const float*)d_in[0];
    const int*   ei  = (const int*)d_in[1];
    const float* act = (const float*)d_in[3];
    const float* Wc1 = (const float*)d_in[4];
    const float* bc1 = (const float*)d_in[5];
    const float* Wc2 = (const float*)d_in[6];
    const float* bc2 = (const float*)d_in[7];
    const float* Wc3 = (const float*)d_in[8];
    const float* bc3 = (const float*)d_in[9];
    const float* Wg1 = (const float*)d_in[10];
    const float* bg1 = (const float*)d_in[11];
    const float* Wg2 = (const float*)d_in[12];
    const float* bg2 = (const float*)d_in[13];
    const float* Wg3 = (const float*)d_in[14];
    const float* bg3 = (const float*)d_in[15];
    float* out = (float*)d_out;

    float* ws   = (float*)d_ws;
    float* dinv = ws;                               // 32000
    float* bufA = dinv + TOTALN;                    // feat A (bf16) / p1 lower
    float* bufB = bufA + (long)TOTALN * 128;        // feat B / p1 upper
    float* hg   = bufB + (long)TOTALN * 128;        // 4096
    float* h1   = hg + 32 * 128;                    // 6144
    float* h2   = h1 + 32 * 192;                    // 6144
    float* csr_w = h2 + 32 * 192;                   // 512000
    float* pp   = csr_w + NE;                       // 102400 (reused as rp for red1a)
    float* hgT  = pp + NB * PCH * 128;              // 4096
    unsigned short* hgB = (unsigned short*)(hgT + 128 * NB);  // 4096 bf16
    int* cnt    = (int*)(hgB + 4096);               // 32000
    int* rowptr = cnt + TOTALN;                     // 32001 (+3 pad)
    int* cursor = rowptr + TOTALN + 4;              // 32000
    int* bsum   = cursor + TOTALN;                  // 128
    int* csr_src= bsum + 128;                       // 512000
    unsigned short* Wt = (unsigned short*)(csr_src + NE);  // 16384 bf16
    unsigned short* fA = (unsigned short*)bufA;
    unsigned short* fB = (unsigned short*)bufB;
    // p1 spans bufA+bufB (6.144M floats <= 8.192M combined); p2 after p1.
    float* p1   = bufA;
    float* p2   = bufA + (long)3 * N_PER * 2048;
    float* rp   = pp;                               // 49152 <= 102400

    // degree + norm + CSR build
    k_init_deg<<<(TOTALN + 255) / 256, 256, 0, stream>>>(dinv);
    k_deg<<<NE / 256, 256, 0, stream>>>(ei, dinv);
    k_prep<<<(TOTALN + 255) / 256, 256, 0, stream>>>(dinv, cnt);
    k_scan_block<<<125, 256, 0, stream>>>(cnt, rowptr, bsum);
    k_scan_tot<<<1, 64, 0, stream>>>(bsum);
    k_scan_add<<<125, 256, 0, stream>>>(rowptr, bsum, cursor);
    k_fill<<<NE / 256, 256, 0, stream>>>(ei, dinv, cursor, csr_src, csr_w);

    // layer 1 (x f32 -> bf16 MFMA)
    k_wcvt<<<64, 256, 0, stream>>>(Wc1, Wt);
    k_mm<1><<<500, 256, 0, stream>>>(x, Wt, fB);
    k_gather<0><<<TOTALN / 4, 256, 0, stream>>>(fB, fA, rowptr, csr_src, csr_w, dinv, bc1);
    // layer 2
    k_wcvt<<<64, 256, 0, stream>>>(Wc2, Wt);
    k_mm<0><<<500, 256, 0, stream>>>(fA, Wt, fB);
    k_gather<0><<<TOTALN / 4, 256, 0, stream>>>(fB, fA, rowptr, csr_src, csr_w, dinv, bc2);
    // layer 3 (no relu; bias folded into pool stage 2)
    k_wcvt<<<64, 256, 0, stream>>>(Wc3, Wt);
    k_mm<0><<<500, 256, 0, stream>>>(fA, Wt, fB);
    k_gather<1><<<TOTALN / 4, 256, 0, stream>>>(fB, fA, rowptr, csr_src, csr_w, dinv, nullptr);
    k_pool1<<<NB * PCH, 256, 0, stream>>>(fA, pp);
    k_pool2<<<(NB * 128 + 255) / 256, 256, 0, stream>>>(pp, bc3, hg, hgT, hgB);

    // hypernetwork + compute_q
    k_w1<<<NH * W1CH, 256, 0, stream>>>(hgB, Wg1, bg1, act, p1);
    k_red1a<<<96 * 8, 256, 0, stream>>>(p1, rp);
    k_red1b<<<24, 256, 0, stream>>>(rp, h1);
    k_w2<<<NH * Dh, 256, 0, stream>>>(hg, Wg2, bg2, h1, p2);
    k_red2<<<24, 256, 0, stream>>>(p2, h2);
    k_out<<<NB, 192, 0, stream>>>(hg, Wg3, bg3, h2, out);
}

// Round 17
// 267.101 us; speedup vs baseline: 1.0547x; 1.0091x over previous
//
#include <hip/hip_runtime.h>
#include <hip/hip_bf16.h>
#include <math.h>

#define NB 32          // graphs
#define N_PER 1000
#define TOTALN 32000
#define NE 512000
#define HID 128
#define Dh 64
#define NH 3
#define EPSV 1e-6f
#define PCH 25         // pool chunks per graph (40 nodes each)
#define W1CH 500       // k_w1 chunks (2 n's each)

typedef __attribute__((ext_vector_type(8))) short bf16x8;
typedef __attribute__((ext_vector_type(4))) float f32x4;

__device__ __forceinline__ float softplusf(float x) {
    return fmaxf(x, 0.0f) + log1pf(expf(-fabsf(x)));
}
__device__ __forceinline__ unsigned short f2b(float f) {
    __hip_bfloat16 h = __float2bfloat16(f);
    return __builtin_bit_cast(unsigned short, h);
}
__device__ __forceinline__ float b2f(unsigned short u) {
    unsigned int x = ((unsigned int)u) << 16;
    return __builtin_bit_cast(float, x);
}

// deg init + h1pre zero
__global__ __launch_bounds__(256) void k_init(float* deg, float* h1pre) {
    int i = blockIdx.x * 256 + threadIdx.x;
    if (i < TOTALN) deg[i] = 1.0f;   // self loop
    if (i < 96 * 64) h1pre[i] = 0.f;
}

__global__ __launch_bounds__(256) void k_deg(const int* __restrict__ ei, float* deg) {
    int e = blockIdx.x * 256 + threadIdx.x;
    if (e < NE) atomicAdd(&deg[ei[NE + e]], 1.0f);
}

// fused: dinv = rsqrt(deg) in place + block-local exclusive scan of (deg-1)
__global__ __launch_bounds__(256) void k_scan1(float* __restrict__ deg,
                                               int* __restrict__ rowptr,
                                               int* __restrict__ bsum) {
    __shared__ int sh[256];
    int t = threadIdx.x;
    int i = blockIdx.x * 256 + t;
    float dv = deg[i];
    int v = (int)dv - 1;
    deg[i] = rsqrtf(dv);
    sh[t] = v;
    __syncthreads();
    for (int off = 1; off < 256; off <<= 1) {
        int add = (t >= off) ? sh[t - off] : 0;
        __syncthreads();
        sh[t] += add;
        __syncthreads();
    }
    rowptr[i] = sh[t] - v;
    if (t == 255) bsum[blockIdx.x] = sh[255];
}

// fused: per-block prefix of bsum + global offset add + cursor copy
__global__ __launch_bounds__(256) void k_scan2(int* __restrict__ rowptr,
                                               const int* __restrict__ bsum,
                                               int* __restrict__ cursor) {
    __shared__ int sh[128];
    __shared__ int spre;
    int t = threadIdx.x, bid = blockIdx.x;
    if (t < 125) sh[t] = bsum[t];
    __syncthreads();
    if (t == 0) {
        int run = 0;
        for (int j = 0; j < bid; ++j) run += sh[j];
        spre = run;
    }
    __syncthreads();
    int i = bid * 256 + t;
    int v = rowptr[i] + spre;
    rowptr[i] = v;
    cursor[i] = v;
    if (i == 0) rowptr[TOTALN] = NE;
}

__global__ __launch_bounds__(256) void k_fill(const int* __restrict__ ei,
                                              const float* __restrict__ dinv,
                                              int* __restrict__ cursor,
                                              int* __restrict__ csr_src,
                                              float* __restrict__ csr_w) {
    int e = blockIdx.x * 256 + threadIdx.x;
    if (e < NE) {
        int s = ei[e], d = ei[NE + e];
        int pos = atomicAdd(&cursor[d], 1);
        csr_src[pos] = s;
        csr_w[pos] = dinv[s] * dinv[d];
    }
}

// transpose+convert ALL THREE W[128][128] f32 -> Wt[layer][c][k] bf16
__global__ __launch_bounds__(256) void k_wcvt3(const float* __restrict__ W1,
                                               const float* __restrict__ W2,
                                               const float* __restrict__ W3,
                                               unsigned short* __restrict__ Wt) {
    int i = blockIdx.x * 256 + threadIdx.x;   // 3*16384
    int w = i >> 14, j = i & 16383;
    const float* W = (w == 0) ? W1 : (w == 1) ? W2 : W3;
    int k = j >> 7, c = j & 127;
    Wt[w * 16384 + c * 128 + k] = f2b(W[j]);
}

// Y[32000 x 128](bf16) = X[32000 x 128] @ W ; MFMA 16x16x32 bf16, no LDS.
template<int INF32>
__global__ __launch_bounds__(256) void k_mm(const void* __restrict__ Xv,
                                            const unsigned short* __restrict__ Wt,
                                            unsigned short* __restrict__ Y) {
    int tid = threadIdx.x;
    int wv = tid >> 6, l = tid & 63;
    int row0 = blockIdx.x * 64 + wv * 16;
    int r = l & 15, kc = l >> 4;
    bf16x8 a[4];
    if (INF32) {
        const float* X = (const float*)Xv;
#pragma unroll
        for (int ks = 0; ks < 4; ++ks) {
            const float* p = X + (long)(row0 + r) * 128 + ks * 32 + kc * 8;
            float4 f0 = *(const float4*)p;
            float4 f1 = *(const float4*)(p + 4);
            bf16x8 t;
            t[0] = (short)f2b(f0.x); t[1] = (short)f2b(f0.y);
            t[2] = (short)f2b(f0.z); t[3] = (short)f2b(f0.w);
            t[4] = (short)f2b(f1.x); t[5] = (short)f2b(f1.y);
            t[6] = (short)f2b(f1.z); t[7] = (short)f2b(f1.w);
            a[ks] = t;
        }
    } else {
        const unsigned short* X = (const unsigned short*)Xv;
#pragma unroll
        for (int ks = 0; ks < 4; ++ks)
            a[ks] = *(const bf16x8*)(X + (long)(row0 + r) * 128 + ks * 32 + kc * 8);
    }
    f32x4 acc[8];
#pragma unroll
    for (int nt = 0; nt < 8; ++nt) acc[nt] = (f32x4){0.f, 0.f, 0.f, 0.f};
#pragma unroll
    for (int ks = 0; ks < 4; ++ks) {
#pragma unroll
        for (int nt = 0; nt < 8; ++nt) {
            bf16x8 b = *(const bf16x8*)(Wt + (nt * 16 + r) * 128 + ks * 32 + kc * 8);
            acc[nt] = __builtin_amdgcn_mfma_f32_16x16x32_bf16(a[ks], b, acc[nt], 0, 0, 0);
        }
    }
#pragma unroll
    for (int nt = 0; nt < 8; ++nt)
#pragma unroll
        for (int j = 0; j < 4; ++j)
            Y[(long)(row0 + kc * 4 + j) * 128 + nt * 16 + r] = f2b(acc[nt][j]);
}

// CSR gather on bf16 features: 1 wave per node, 4B per lane, 4-deep ILP.
template<int MODE>
__global__ __launch_bounds__(256) void k_gather(const unsigned short* __restrict__ feat,
                                                unsigned short* __restrict__ out,
                                                const int* __restrict__ rowptr,
                                                const int* __restrict__ csr_src,
                                                const float* __restrict__ csr_w,
                                                const float* __restrict__ dinv,
                                                const float* __restrict__ bias) {
    int wid = threadIdx.x >> 6, lane = threadIdx.x & 63;
    int v = blockIdx.x * 4 + wid;
    const unsigned int* f2 = (const unsigned int*)feat;
    float dv = dinv[v];
    unsigned int sv = f2[v * 64 + lane];
    float acc0 = b2f((unsigned short)(sv & 0xffff)) * dv * dv;
    float acc1 = b2f((unsigned short)(sv >> 16)) * dv * dv;
    int e = rowptr[v], e1 = rowptr[v + 1];
    for (; e + 4 <= e1; e += 4) {
        int s0 = csr_src[e], s1 = csr_src[e + 1], s2 = csr_src[e + 2], s3 = csr_src[e + 3];
        float w0 = csr_w[e], w1 = csr_w[e + 1], w2 = csr_w[e + 2], w3 = csr_w[e + 3];
        unsigned int u0 = f2[s0 * 64 + lane];
        unsigned int u1 = f2[s1 * 64 + lane];
        unsigned int u2 = f2[s2 * 64 + lane];
        unsigned int u3 = f2[s3 * 64 + lane];
        acc0 += b2f((unsigned short)(u0 & 0xffff)) * w0 + b2f((unsigned short)(u1 & 0xffff)) * w1
              + b2f((unsigned short)(u2 & 0xffff)) * w2 + b2f((unsigned short)(u3 & 0xffff)) * w3;
        acc1 += b2f((unsigned short)(u0 >> 16)) * w0 + b2f((unsigned short)(u1 >> 16)) * w1
              + b2f((unsigned short)(u2 >> 16)) * w2 + b2f((unsigned short)(u3 >> 16)) * w3;
    }
    for (; e < e1; ++e) {
        int s = csr_src[e];
        float w = csr_w[e];
        unsigned int u = f2[s * 64 + lane];
        acc0 += b2f((unsigned short)(u & 0xffff)) * w;
        acc1 += b2f((unsigned short)(u >> 16)) * w;
    }
    if (MODE == 0) {
        int c = lane * 2;
        acc0 = fmaxf(acc0 + bias[c], 0.f);
        acc1 = fmaxf(acc1 + bias[c + 1], 0.f);
    }
    ((unsigned int*)out)[v * 64 + lane] =
        (unsigned int)f2b(acc0) | ((unsigned int)f2b(acc1) << 16);
}

// pool stage 1 (bf16 input)
__global__ __launch_bounds__(256) void k_pool1(const unsigned short* __restrict__ A,
                                               float* __restrict__ pp) {
    __shared__ float sh[256];
    int b = blockIdx.x / PCH, ch = blockIdx.x % PCH;
    int c = threadIdx.x & 127, half = threadIdx.x >> 7;
    float acc = 0.f;
    int n0 = ch * 40;
#pragma unroll 4
    for (int j = half; j < 40; j += 2)
        acc += b2f(A[(long)(b * N_PER + n0 + j) * 128 + c]);
    sh[threadIdx.x] = acc;
    __syncthreads();
    if (threadIdx.x < 128)
        pp[blockIdx.x * 128 + c] = sh[c] + sh[128 + c];
}

// pool stage 2: mean + layer-3 bias; writes hg (f32) + hgB (bf16)
__global__ __launch_bounds__(256) void k_pool2(const float* __restrict__ pp,
                                               const float* __restrict__ bias,
                                               float* __restrict__ hg,
                                               unsigned short* __restrict__ hgB) {
    int i = blockIdx.x * 256 + threadIdx.x;
    if (i >= NB * 128) return;
    int b = i >> 7, c = i & 127;
    float s = 0.f;
#pragma unroll
    for (int ch = 0; ch < PCH; ++ch)
        s += pp[(b * PCH + ch) * 128 + c];
    float v = s * (1.0f / N_PER) + bias[c];
    hg[i] = v;
    hgB[i] = f2b(v);
}

// k_w1 v2 (MFMA + joint 2-n staging): block = (h, chunk of 2 n); 4 waves.
// BOTH n's staged in ONE pass with float4 global reads: for each k, the 2
// adjacent n's form a 512B contiguous segment (Wg1 layout [k][h][n][d]).
// 16 iters x 8 k's x float4. ONE barrier per block. Then each wave computes
// its 16-d slice of each n from LDS (bf16x8 reads, row stride 136 shorts).
__global__ __launch_bounds__(256) void k_w1(const unsigned short* __restrict__ hgB,
                                            const float* __restrict__ Wg1,
                                            const float* __restrict__ bg1,
                                            const float* __restrict__ actions,
                                            float* __restrict__ p1) {
    __shared__ unsigned short wt[2][64][136];
    int h = blockIdx.x / W1CH, chunk = blockIdx.x % W1CH;
    int tid = threadIdx.x;
    int wv = tid >> 6, l = tid & 63;
    int r = l & 15, kc = l >> 4;
    const long KS = (long)NH * N_PER * Dh;            // 192000
    int n0 = chunk * 2;
    long colbase2 = (long)h * (N_PER * Dh) + (long)n0 * Dh;
    bf16x8 a[2][4];
#pragma unroll
    for (int mt = 0; mt < 2; ++mt)
#pragma unroll
        for (int ks = 0; ks < 4; ++ks)
            a[mt][ks] = *(const bf16x8*)(hgB + (mt * 16 + r) * 128 + ks * 32 + kc * 8);
    // staging: thread -> (k-offset, j); j indexes [n', d] across both n's
    int kq = tid >> 5;            // 0..7
    int j = (tid & 31) * 4;       // 0..124, step 4
    int ns = j >> 6, ds = j & 63;
#pragma unroll 4
    for (int it = 0; it < 16; ++it) {
        int k = it * 8 + kq;
        float4 v = *(const float4*)(Wg1 + (long)k * KS + colbase2 + j);
        wt[ns][ds][k]     = f2b(v.x);
        wt[ns][ds + 1][k] = f2b(v.y);
        wt[ns][ds + 2][k] = f2b(v.z);
        wt[ns][ds + 3][k] = f2b(v.w);
    }
    __syncthreads();
#pragma unroll
    for (int nn = 0; nn < 2; ++nn) {
        int n = n0 + nn;
        f32x4 acc0 = (f32x4){0.f, 0.f, 0.f, 0.f};
        f32x4 acc1 = (f32x4){0.f, 0.f, 0.f, 0.f};
#pragma unroll
        for (int ks = 0; ks < 4; ++ks) {
            bf16x8 bb = *(const bf16x8*)&wt[nn][wv * 16 + r][ks * 32 + kc * 8];
            acc0 = __builtin_amdgcn_mfma_f32_16x16x32_bf16(a[0][ks], bb, acc0, 0, 0, 0);
            acc1 = __builtin_amdgcn_mfma_f32_16x16x32_bf16(a[1][ks], bb, acc1, 0, 0, 0);
        }
        float bgv = bg1[colbase2 + nn * 64 + wv * 16 + r];
        float* po = p1 + ((long)h * N_PER + n) * 2048;
#pragma unroll
        for (int jj = 0; jj < 4; ++jj) {
            int b0 = kc * 4 + jj;
            int b1 = 16 + kc * 4 + jj;
            po[b0 * 64 + wv * 16 + r] = softplusf(acc0[jj] + bgv) * actions[b0 * N_PER + n];
            po[b1 * 64 + wv * 16 + r] = softplusf(acc1[jj] + bgv) * actions[b1 * N_PER + n];
        }
    }
}

// red1: grid 96*8; block = (bh, seg of 125 n); atomic-accumulate into h1pre
__global__ __launch_bounds__(256) void k_red1a(const float* __restrict__ p1,
                                               float* __restrict__ h1pre) {
    __shared__ float sh[4][64];
    int bh = blockIdx.x >> 3, seg = blockIdx.x & 7;   // bh = b*3+h
    int b = bh / 3, h = bh % 3;
    int part = threadIdx.x >> 6, d = threadIdx.x & 63;
    const float* base = p1 + (long)h * N_PER * 2048 + b * 64 + d;
    float s = 0.f;
    for (int n = seg * 125 + part; n < seg * 125 + 125; n += 4)
        s += base[(long)n * 2048];
    if (part) sh[part][d] = s;
    __syncthreads();
    if (part == 0)
        atomicAdd(&h1pre[bh * 64 + d], s + sh[1][d] + sh[2][d] + sh[3][d]);
}

// k_w2: SafeSqrt applied on h1pre load (red1b folded in)
__global__ __launch_bounds__(256) void k_w2(const float* __restrict__ hg,
                                            const float* __restrict__ Wg2,
                                            const float* __restrict__ bg2,
                                            const float* __restrict__ h1pre,
                                            float* __restrict__ p2) {
    __shared__ float hgs[32][128];
    __shared__ float wt[128][64];
    __shared__ float h1s[32];
    int hd = blockIdx.x;
    int tid = threadIdx.x;
    for (int i = 0; i < 16; ++i) {
        int idx = tid + i * 256;
        hgs[idx >> 7][idx & 127] = hg[idx];
    }
    long base = (long)hd * 64;
    for (int i = 0; i < 32; ++i) {
        int idx = tid + i * 256;
        wt[idx >> 6][idx & 63] = Wg2[(long)(idx >> 6) * (NH * Dh * Dh) + base + (idx & 63)];
    }
    int h = hd >> 6, d = hd & 63;
    if (tid < 32)
        h1s[tid] = sqrtf(fmaxf(h1pre[(tid * 3 + h) * 64 + d], 0.f) + EPSV);
    __syncthreads();
    int e = tid & 63, bq = tid >> 6;
    float bgv = bg2[base + e];
    float dot[8];
#pragma unroll
    for (int bi = 0; bi < 8; ++bi) dot[bi] = 0.f;
    for (int k = 0; k < 128; ++k) {
        float w = wt[k][e];
#pragma unroll
        for (int bi = 0; bi < 8; ++bi)
            dot[bi] += hgs[bq * 8 + bi][k] * w;
    }
    float* po = p2 + (long)hd * (32 * 64);
#pragma unroll
    for (int bi = 0; bi < 8; ++bi) {
        int b = bq * 8 + bi;
        po[b * 64 + e] = softplusf(dot[bi] + bgv) * h1s[b];
    }
}

// k_out: red2 (d-sum + SafeLog) folded in
__global__ __launch_bounds__(192) void k_out(const float* __restrict__ hg,
                                             const float* __restrict__ Wg3,
                                             const float* __restrict__ bg3,
                                             const float* __restrict__ p2,
                                             float* __restrict__ out) {
    __shared__ float hgb[128];
    __shared__ float hres[NH];
    int b = blockIdx.x, tid = threadIdx.x;
    if (tid < 128) hgb[tid] = hg[b * 128 + tid];
    __syncthreads();
    int h = tid / 64, e = tid & 63;
    int c = h * 64 + e;
    float s = 0.f;
#pragma unroll 8
    for (int d = 0; d < 64; ++d)
        s += p2[(long)(h * 64 + d) * 2048 + b * 64 + e];
    float h2v = log1pf(fmaxf(s, 0.f));
    float dot = 0.f;
    for (int k = 0; k < 128; ++k)
        dot += hgb[k] * Wg3[k * (NH * Dh) + c];
    float v = softplusf(dot + bg3[c]) * h2v;
    for (int off = 32; off; off >>= 1)
        v += __shfl_down(v, off, 64);
    if (e == 0) hres[h] = v;
    __syncthreads();
    if (tid == 0) out[b] = fminf(fminf(hres[0], hres[1]), hres[2]);
}

extern "C" void kernel_launch(void* const* d_in, const int* in_sizes, int n_in,
                              void* d_out, int out_size, void* d_ws, size_t ws_size,
                              hipStream_t stream) {
    const float* x   = (const float*)d_in[0];
    const int*   ei  = (const int*)d_in[1];
    const float* act = (const float*)d_in[3];
    const float* Wc1 = (const float*)d_in[4];
    const float* bc1 = (const float*)d_in[5];
    const float* Wc2 = (const float*)d_in[6];
    const float* bc2 = (const float*)d_in[7];
    const float* Wc3 = (const float*)d_in[8];
    const float* bc3 = (const float*)d_in[9];
    const float* Wg1 = (const float*)d_in[10];
    const float* bg1 = (const float*)d_in[11];
    const float* Wg2 = (const float*)d_in[12];
    const float* bg2 = (const float*)d_in[13];
    const float* Wg3 = (const float*)d_in[14];
    const float* bg3 = (const float*)d_in[15];
    float* out = (float*)d_out;

    float* ws   = (float*)d_ws;
    float* dinv = ws;                               // 32000 (deg -> dinv in place)
    float* bufA = dinv + TOTALN;                    // feat A (bf16) / p1 lower
    float* bufB = bufA + (long)TOTALN * 128;        // feat B / p1 upper
    float* hg   = bufB + (long)TOTALN * 128;        // 4096
    float* h1pre = hg + 32 * 128;                   // 6144 (atomic accumulator)
    float* csr_w = h1pre + 96 * 64;                 // 512000
    float* pp   = csr_w + NE;                       // 102400
    unsigned short* hgB = (unsigned short*)(pp + NB * PCH * 128);  // 4096 bf16
    int* rowptr = (int*)(hgB + 4096);               // 32001 (+3 pad)
    int* cursor = rowptr + TOTALN + 4;              // 32000
    int* bsum   = cursor + TOTALN;                  // 128
    int* csr_src= bsum + 128;                       // 512000
    unsigned short* Wt = (unsigned short*)(csr_src + NE);  // 3*16384 bf16
    unsigned short* fA = (unsigned short*)bufA;
    unsigned short* fB = (unsigned short*)bufB;
    // p1 spans bufA+bufB (6.144M floats <= 8.192M combined); p2 after p1.
    float* p1   = bufA;
    float* p2   = bufA + (long)3 * N_PER * 2048;

    // CSR build (5 kernels)
    k_init<<<(TOTALN + 255) / 256, 256, 0, stream>>>(dinv, h1pre);
    k_deg<<<NE / 256, 256, 0, stream>>>(ei, dinv);
    k_scan1<<<125, 256, 0, stream>>>(dinv, rowptr, bsum);
    k_scan2<<<125, 256, 0, stream>>>(rowptr, bsum, cursor);
    k_fill<<<NE / 256, 256, 0, stream>>>(ei, dinv, cursor, csr_src, csr_w);
    k_wcvt3<<<192, 256, 0, stream>>>(Wc1, Wc2, Wc3, Wt);

    // layer 1 (x f32 -> bf16 MFMA)
    k_mm<1><<<500, 256, 0, stream>>>(x, Wt, fB);
    k_gather<0><<<TOTALN / 4, 256, 0, stream>>>(fB, fA, rowptr, csr_src, csr_w, dinv, bc1);
    // layer 2
    k_mm<0><<<500, 256, 0, stream>>>(fA, Wt + 16384, fB);
    k_gather<0><<<TOTALN / 4, 256, 0, stream>>>(fB, fA, rowptr, csr_src, csr_w, dinv, bc2);
    // layer 3 (no relu; bias folded into pool stage 2)
    k_mm<0><<<500, 256, 0, stream>>>(fA, Wt + 32768, fB);
    k_gather<1><<<TOTALN / 4, 256, 0, stream>>>(fB, fA, rowptr, csr_src, csr_w, dinv, nullptr);
    k_pool1<<<NB * PCH, 256, 0, stream>>>(fA, pp);
    k_pool2<<<(NB * 128 + 255) / 256, 256, 0, stream>>>(pp, bc3, hg, hgB);

    // hypernetwork + compute_q
    k_w1<<<NH * W1CH, 256, 0, stream>>>(hgB, Wg1, bg1, act, p1);
    k_red1a<<<96 * 8, 256, 0, stream>>>(p1, h1pre);
    k_w2<<<NH * Dh, 256, 0, stream>>>(hg, Wg2, bg2, h1pre, p2);
    k_out<<<NB, 192, 0, stream>>>(hg, Wg3, bg3, p2, out);
}

// Round 18
// 259.409 us; speedup vs baseline: 1.0859x; 1.0297x over previous
//
#include <hip/hip_runtime.h>
#include <hip/hip_bf16.h>
#include <math.h>

#define NB 32          // graphs
#define N_PER 1000
#define TOTALN 32000
#define NE 512000
#define HID 128
#define Dh 64
#define NH 3
#define EPSV 1e-6f
#define PCH 25         // pool chunks per graph (40 nodes each)
#define W1CH 500       // k_w1 chunks (2 n's each)

typedef __attribute__((ext_vector_type(8))) short bf16x8;
typedef __attribute__((ext_vector_type(4))) float f32x4;

__device__ __forceinline__ float softplusf(float x) {
    return fmaxf(x, 0.0f) + log1pf(expf(-fabsf(x)));
}
__device__ __forceinline__ unsigned short f2b(float f) {
    __hip_bfloat16 h = __float2bfloat16(f);
    return __builtin_bit_cast(unsigned short, h);
}
__device__ __forceinline__ float b2f(unsigned short u) {
    unsigned int x = ((unsigned int)u) << 16;
    return __builtin_bit_cast(float, x);
}

// deg init + h1pre zero
__global__ __launch_bounds__(256) void k_init(float* deg, float* h1pre) {
    int i = blockIdx.x * 256 + threadIdx.x;
    if (i < TOTALN) deg[i] = 1.0f;   // self loop
    if (i < 96 * 64) h1pre[i] = 0.f;
}

__global__ __launch_bounds__(256) void k_deg(const int* __restrict__ ei, float* deg) {
    int e = blockIdx.x * 256 + threadIdx.x;
    if (e < NE) atomicAdd(&deg[ei[NE + e]], 1.0f);
}

// fused: dinv = rsqrt(deg) in place + block-local exclusive scan of (deg-1)
__global__ __launch_bounds__(256) void k_scan1(float* __restrict__ deg,
                                               int* __restrict__ rowptr,
                                               int* __restrict__ bsum) {
    __shared__ int sh[256];
    int t = threadIdx.x;
    int i = blockIdx.x * 256 + t;
    float dv = deg[i];
    int v = (int)dv - 1;
    deg[i] = rsqrtf(dv);
    sh[t] = v;
    __syncthreads();
    for (int off = 1; off < 256; off <<= 1) {
        int add = (t >= off) ? sh[t - off] : 0;
        __syncthreads();
        sh[t] += add;
        __syncthreads();
    }
    rowptr[i] = sh[t] - v;
    if (t == 255) bsum[blockIdx.x] = sh[255];
}

// fused: per-block prefix of bsum + global offset add + cursor copy
__global__ __launch_bounds__(256) void k_scan2(int* __restrict__ rowptr,
                                               const int* __restrict__ bsum,
                                               int* __restrict__ cursor) {
    __shared__ int sh[128];
    __shared__ int spre;
    int t = threadIdx.x, bid = blockIdx.x;
    if (t < 125) sh[t] = bsum[t];
    __syncthreads();
    if (t == 0) {
        int run = 0;
        for (int j = 0; j < bid; ++j) run += sh[j];
        spre = run;
    }
    __syncthreads();
    int i = bid * 256 + t;
    int v = rowptr[i] + spre;
    rowptr[i] = v;
    cursor[i] = v;
    if (i == 0) rowptr[TOTALN] = NE;
}

__global__ __launch_bounds__(256) void k_fill(const int* __restrict__ ei,
                                              const float* __restrict__ dinv,
                                              int* __restrict__ cursor,
                                              int* __restrict__ csr_src,
                                              float* __restrict__ csr_w) {
    int e = blockIdx.x * 256 + threadIdx.x;
    if (e < NE) {
        int s = ei[e], d = ei[NE + e];
        int pos = atomicAdd(&cursor[d], 1);
        csr_src[pos] = s;
        csr_w[pos] = dinv[s] * dinv[d];
    }
}

// transpose+convert ALL THREE W[128][128] f32 -> Wt[layer][c][k] bf16
__global__ __launch_bounds__(256) void k_wcvt3(const float* __restrict__ W1,
                                               const float* __restrict__ W2,
                                               const float* __restrict__ W3,
                                               unsigned short* __restrict__ Wt) {
    int i = blockIdx.x * 256 + threadIdx.x;   // 3*16384
    int w = i >> 14, j = i & 16383;
    const float* W = (w == 0) ? W1 : (w == 1) ? W2 : W3;
    int k = j >> 7, c = j & 127;
    Wt[w * 16384 + c * 128 + k] = f2b(W[j]);
}

// Y[32000 x 128](bf16) = X[32000 x 128] @ W ; MFMA 16x16x32 bf16, no LDS.
template<int INF32>
__global__ __launch_bounds__(256) void k_mm(const void* __restrict__ Xv,
                                            const unsigned short* __restrict__ Wt,
                                            unsigned short* __restrict__ Y) {
    int tid = threadIdx.x;
    int wv = tid >> 6, l = tid & 63;
    int row0 = blockIdx.x * 64 + wv * 16;
    int r = l & 15, kc = l >> 4;
    bf16x8 a[4];
    if (INF32) {
        const float* X = (const float*)Xv;
#pragma unroll
        for (int ks = 0; ks < 4; ++ks) {
            const float* p = X + (long)(row0 + r) * 128 + ks * 32 + kc * 8;
            float4 f0 = *(const float4*)p;
            float4 f1 = *(const float4*)(p + 4);
            bf16x8 t;
            t[0] = (short)f2b(f0.x); t[1] = (short)f2b(f0.y);
            t[2] = (short)f2b(f0.z); t[3] = (short)f2b(f0.w);
            t[4] = (short)f2b(f1.x); t[5] = (short)f2b(f1.y);
            t[6] = (short)f2b(f1.z); t[7] = (short)f2b(f1.w);
            a[ks] = t;
        }
    } else {
        const unsigned short* X = (const unsigned short*)Xv;
#pragma unroll
        for (int ks = 0; ks < 4; ++ks)
            a[ks] = *(const bf16x8*)(X + (long)(row0 + r) * 128 + ks * 32 + kc * 8);
    }
    f32x4 acc[8];
#pragma unroll
    for (int nt = 0; nt < 8; ++nt) acc[nt] = (f32x4){0.f, 0.f, 0.f, 0.f};
#pragma unroll
    for (int ks = 0; ks < 4; ++ks) {
#pragma unroll
        for (int nt = 0; nt < 8; ++nt) {
            bf16x8 b = *(const bf16x8*)(Wt + (nt * 16 + r) * 128 + ks * 32 + kc * 8);
            acc[nt] = __builtin_amdgcn_mfma_f32_16x16x32_bf16(a[ks], b, acc[nt], 0, 0, 0);
        }
    }
#pragma unroll
    for (int nt = 0; nt < 8; ++nt)
#pragma unroll
        for (int j = 0; j < 4; ++j)
            Y[(long)(row0 + kc * 4 + j) * 128 + nt * 16 + r] = f2b(acc[nt][j]);
}

// CSR gather, paired-edge: wave = 1 node; two 32-lane halves own alternate
// edges; each half loads its row as uint2 (8B/lane -> 2 rows = 512B per
// instruction). 4-deep ILP => 8 edges in flight/wave. Halves combined via
// one shfl_xor(32); lanes 0-31 store the packed row.
template<int MODE>
__global__ __launch_bounds__(256) void k_gather(const unsigned short* __restrict__ feat,
                                                unsigned short* __restrict__ out,
                                                const int* __restrict__ rowptr,
                                                const int* __restrict__ csr_src,
                                                const float* __restrict__ csr_w,
                                                const float* __restrict__ dinv,
                                                const float* __restrict__ bias) {
    int wid = threadIdx.x >> 6, lane = threadIdx.x & 63;
    int half = lane >> 5, li = lane & 31;
    int v = blockIdx.x * 4 + wid;
    const uint2* f4 = (const uint2*)feat;   // 8B = 4 bf16 per lane; row = 32 uint2
    float dv = dinv[v];
    uint2 sv = f4[v * 32 + li];
    float sw = half ? 0.f : dv * dv;        // self-loop counted once
    float a0 = b2f((unsigned short)(sv.x & 0xffff)) * sw;
    float a1 = b2f((unsigned short)(sv.x >> 16)) * sw;
    float a2 = b2f((unsigned short)(sv.y & 0xffff)) * sw;
    float a3 = b2f((unsigned short)(sv.y >> 16)) * sw;
    int e1 = rowptr[v + 1];
    int i = rowptr[v] + half;               // this half's edges: i, i+2, i+4, ...
    for (; i + 6 < e1; i += 8) {
        int s0 = csr_src[i], s1 = csr_src[i + 2], s2 = csr_src[i + 4], s3 = csr_src[i + 6];
        float w0 = csr_w[i], w1 = csr_w[i + 2], w2 = csr_w[i + 4], w3 = csr_w[i + 6];
        uint2 u0 = f4[s0 * 32 + li];
        uint2 u1 = f4[s1 * 32 + li];
        uint2 u2 = f4[s2 * 32 + li];
        uint2 u3 = f4[s3 * 32 + li];
        a0 += b2f((unsigned short)(u0.x & 0xffff)) * w0 + b2f((unsigned short)(u1.x & 0xffff)) * w1
            + b2f((unsigned short)(u2.x & 0xffff)) * w2 + b2f((unsigned short)(u3.x & 0xffff)) * w3;
        a1 += b2f((unsigned short)(u0.x >> 16)) * w0 + b2f((unsigned short)(u1.x >> 16)) * w1
            + b2f((unsigned short)(u2.x >> 16)) * w2 + b2f((unsigned short)(u3.x >> 16)) * w3;
        a2 += b2f((unsigned short)(u0.y & 0xffff)) * w0 + b2f((unsigned short)(u1.y & 0xffff)) * w1
            + b2f((unsigned short)(u2.y & 0xffff)) * w2 + b2f((unsigned short)(u3.y & 0xffff)) * w3;
        a3 += b2f((unsigned short)(u0.y >> 16)) * w0 + b2f((unsigned short)(u1.y >> 16)) * w1
            + b2f((unsigned short)(u2.y >> 16)) * w2 + b2f((unsigned short)(u3.y >> 16)) * w3;
    }
    for (; i < e1; i += 2) {
        int s = csr_src[i];
        float w = csr_w[i];
        uint2 u = f4[s * 32 + li];
        a0 += b2f((unsigned short)(u.x & 0xffff)) * w;
        a1 += b2f((unsigned short)(u.x >> 16)) * w;
        a2 += b2f((unsigned short)(u.y & 0xffff)) * w;
        a3 += b2f((unsigned short)(u.y >> 16)) * w;
    }
    // combine the two halves (lane L += lane L^32)
    a0 += __shfl_xor(a0, 32, 64);
    a1 += __shfl_xor(a1, 32, 64);
    a2 += __shfl_xor(a2, 32, 64);
    a3 += __shfl_xor(a3, 32, 64);
    if (half == 0) {
        if (MODE == 0) {
            int c = li * 4;
            a0 = fmaxf(a0 + bias[c], 0.f);
            a1 = fmaxf(a1 + bias[c + 1], 0.f);
            a2 = fmaxf(a2 + bias[c + 2], 0.f);
            a3 = fmaxf(a3 + bias[c + 3], 0.f);
        }
        uint2 o;
        o.x = (unsigned int)f2b(a0) | ((unsigned int)f2b(a1) << 16);
        o.y = (unsigned int)f2b(a2) | ((unsigned int)f2b(a3) << 16);
        ((uint2*)out)[v * 32 + li] = o;
    }
}

// pool stage 1 (bf16 input)
__global__ __launch_bounds__(256) void k_pool1(const unsigned short* __restrict__ A,
                                               float* __restrict__ pp) {
    __shared__ float sh[256];
    int b = blockIdx.x / PCH, ch = blockIdx.x % PCH;
    int c = threadIdx.x & 127, half = threadIdx.x >> 7;
    float acc = 0.f;
    int n0 = ch * 40;
#pragma unroll 4
    for (int j = half; j < 40; j += 2)
        acc += b2f(A[(long)(b * N_PER + n0 + j) * 128 + c]);
    sh[threadIdx.x] = acc;
    __syncthreads();
    if (threadIdx.x < 128)
        pp[blockIdx.x * 128 + c] = sh[c] + sh[128 + c];
}

// pool stage 2: mean + layer-3 bias; writes hg (f32) + hgB (bf16)
__global__ __launch_bounds__(256) void k_pool2(const float* __restrict__ pp,
                                               const float* __restrict__ bias,
                                               float* __restrict__ hg,
                                               unsigned short* __restrict__ hgB) {
    int i = blockIdx.x * 256 + threadIdx.x;
    if (i >= NB * 128) return;
    int b = i >> 7, c = i & 127;
    float s = 0.f;
#pragma unroll
    for (int ch = 0; ch < PCH; ++ch)
        s += pp[(b * PCH + ch) * 128 + c];
    float v = s * (1.0f / N_PER) + bias[c];
    hg[i] = v;
    hgB[i] = f2b(v);
}

// k_w1 v2 (MFMA + joint 2-n staging): block = (h, chunk of 2 n); 4 waves.
__global__ __launch_bounds__(256) void k_w1(const unsigned short* __restrict__ hgB,
                                            const float* __restrict__ Wg1,
                                            const float* __restrict__ bg1,
                                            const float* __restrict__ actions,
                                            float* __restrict__ p1) {
    __shared__ unsigned short wt[2][64][136];
    int h = blockIdx.x / W1CH, chunk = blockIdx.x % W1CH;
    int tid = threadIdx.x;
    int wv = tid >> 6, l = tid & 63;
    int r = l & 15, kc = l >> 4;
    const long KS = (long)NH * N_PER * Dh;            // 192000
    int n0 = chunk * 2;
    long colbase2 = (long)h * (N_PER * Dh) + (long)n0 * Dh;
    bf16x8 a[2][4];
#pragma unroll
    for (int mt = 0; mt < 2; ++mt)
#pragma unroll
        for (int ks = 0; ks < 4; ++ks)
            a[mt][ks] = *(const bf16x8*)(hgB + (mt * 16 + r) * 128 + ks * 32 + kc * 8);
    int kq = tid >> 5;            // 0..7
    int j = (tid & 31) * 4;       // 0..124, step 4
    int ns = j >> 6, ds = j & 63;
#pragma unroll 4
    for (int it = 0; it < 16; ++it) {
        int k = it * 8 + kq;
        float4 v = *(const float4*)(Wg1 + (long)k * KS + colbase2 + j);
        wt[ns][ds][k]     = f2b(v.x);
        wt[ns][ds + 1][k] = f2b(v.y);
        wt[ns][ds + 2][k] = f2b(v.z);
        wt[ns][ds + 3][k] = f2b(v.w);
    }
    __syncthreads();
#pragma unroll
    for (int nn = 0; nn < 2; ++nn) {
        int n = n0 + nn;
        f32x4 acc0 = (f32x4){0.f, 0.f, 0.f, 0.f};
        f32x4 acc1 = (f32x4){0.f, 0.f, 0.f, 0.f};
#pragma unroll
        for (int ks = 0; ks < 4; ++ks) {
            bf16x8 bb = *(const bf16x8*)&wt[nn][wv * 16 + r][ks * 32 + kc * 8];
            acc0 = __builtin_amdgcn_mfma_f32_16x16x32_bf16(a[0][ks], bb, acc0, 0, 0, 0);
            acc1 = __builtin_amdgcn_mfma_f32_16x16x32_bf16(a[1][ks], bb, acc1, 0, 0, 0);
        }
        float bgv = bg1[colbase2 + nn * 64 + wv * 16 + r];
        float* po = p1 + ((long)h * N_PER + n) * 2048;
#pragma unroll
        for (int jj = 0; jj < 4; ++jj) {
            int b0 = kc * 4 + jj;
            int b1 = 16 + kc * 4 + jj;
            po[b0 * 64 + wv * 16 + r] = softplusf(acc0[jj] + bgv) * actions[b0 * N_PER + n];
            po[b1 * 64 + wv * 16 + r] = softplusf(acc1[jj] + bgv) * actions[b1 * N_PER + n];
        }
    }
}

// red1: grid 96*8; block = (bh, seg of 125 n); atomic-accumulate into h1pre
__global__ __launch_bounds__(256) void k_red1a(const float* __restrict__ p1,
                                               float* __restrict__ h1pre) {
    __shared__ float sh[4][64];
    int bh = blockIdx.x >> 3, seg = blockIdx.x & 7;   // bh = b*3+h
    int b = bh / 3, h = bh % 3;
    int part = threadIdx.x >> 6, d = threadIdx.x & 63;
    const float* base = p1 + (long)h * N_PER * 2048 + b * 64 + d;
    float s = 0.f;
    for (int n = seg * 125 + part; n < seg * 125 + 125; n += 4)
        s += base[(long)n * 2048];
    if (part) sh[part][d] = s;
    __syncthreads();
    if (part == 0)
        atomicAdd(&h1pre[bh * 64 + d], s + sh[1][d] + sh[2][d] + sh[3][d]);
}

// k_w2: SafeSqrt applied on h1pre load
__global__ __launch_bounds__(256) void k_w2(const float* __restrict__ hg,
                                            const float* __restrict__ Wg2,
                                            const float* __restrict__ bg2,
                                            const float* __restrict__ h1pre,
                                            float* __restrict__ p2) {
    __shared__ float hgs[32][128];
    __shared__ float wt[128][64];
    __shared__ float h1s[32];
    int hd = blockIdx.x;
    int tid = threadIdx.x;
    for (int i = 0; i < 16; ++i) {
        int idx = tid + i * 256;
        hgs[idx >> 7][idx & 127] = hg[idx];
    }
    long base = (long)hd * 64;
    for (int i = 0; i < 32; ++i) {
        int idx = tid + i * 256;
        wt[idx >> 6][idx & 63] = Wg2[(long)(idx >> 6) * (NH * Dh * Dh) + base + (idx & 63)];
    }
    int h = hd >> 6, d = hd & 63;
    if (tid < 32)
        h1s[tid] = sqrtf(fmaxf(h1pre[(tid * 3 + h) * 64 + d], 0.f) + EPSV);
    __syncthreads();
    int e = tid & 63, bq = tid >> 6;
    float bgv = bg2[base + e];
    float dot[8];
#pragma unroll
    for (int bi = 0; bi < 8; ++bi) dot[bi] = 0.f;
    for (int k = 0; k < 128; ++k) {
        float w = wt[k][e];
#pragma unroll
        for (int bi = 0; bi < 8; ++bi)
            dot[bi] += hgs[bq * 8 + bi][k] * w;
    }
    float* po = p2 + (long)hd * (32 * 64);
#pragma unroll
    for (int bi = 0; bi < 8; ++bi) {
        int b = bq * 8 + bi;
        po[b * 64 + e] = softplusf(dot[bi] + bgv) * h1s[b];
    }
}

// k_out: red2 (d-sum + SafeLog) folded in
__global__ __launch_bounds__(192) void k_out(const float* __restrict__ hg,
                                             const float* __restrict__ Wg3,
                                             const float* __restrict__ bg3,
                                             const float* __restrict__ p2,
                                             float* __restrict__ out) {
    __shared__ float hgb[128];
    __shared__ float hres[NH];
    int b = blockIdx.x, tid = threadIdx.x;
    if (tid < 128) hgb[tid] = hg[b * 128 + tid];
    __syncthreads();
    int h = tid / 64, e = tid & 63;
    int c = h * 64 + e;
    float s = 0.f;
#pragma unroll 8
    for (int d = 0; d < 64; ++d)
        s += p2[(long)(h * 64 + d) * 2048 + b * 64 + e];
    float h2v = log1pf(fmaxf(s, 0.f));
    float dot = 0.f;
    for (int k = 0; k < 128; ++k)
        dot += hgb[k] * Wg3[k * (NH * Dh) + c];
    float v = softplusf(dot + bg3[c]) * h2v;
    for (int off = 32; off; off >>= 1)
        v += __shfl_down(v, off, 64);
    if (e == 0) hres[h] = v;
    __syncthreads();
    if (tid == 0) out[b] = fminf(fminf(hres[0], hres[1]), hres[2]);
}

extern "C" void kernel_launch(void* const* d_in, const int* in_sizes, int n_in,
                              void* d_out, int out_size, void* d_ws, size_t ws_size,
                              hipStream_t stream) {
    const float* x   = (const float*)d_in[0];
    const int*   ei  = (const int*)d_in[1];
    const float* act = (const float*)d_in[3];
    const float* Wc1 = (const float*)d_in[4];
    const float* bc1 = (const float*)d_in[5];
    const float* Wc2 = (const float*)d_in[6];
    const float* bc2 = (const float*)d_in[7];
    const float* Wc3 = (const float*)d_in[8];
    const float* bc3 = (const float*)d_in[9];
    const float* Wg1 = (const float*)d_in[10];
    const float* bg1 = (const float*)d_in[11];
    const float* Wg2 = (const float*)d_in[12];
    const float* bg2 = (const float*)d_in[13];
    const float* Wg3 = (const float*)d_in[14];
    const float* bg3 = (const float*)d_in[15];
    float* out = (float*)d_out;

    float* ws   = (float*)d_ws;
    float* dinv = ws;                               // 32000 (deg -> dinv in place)
    float* bufA = dinv + TOTALN;                    // feat A (bf16) / p1 lower
    float* bufB = bufA + (long)TOTALN * 128;        // feat B / p1 upper
    float* hg   = bufB + (long)TOTALN * 128;        // 4096
    float* h1pre = hg + 32 * 128;                   // 6144 (atomic accumulator)
    float* csr_w = h1pre + 96 * 64;                 // 512000
    float* pp   = csr_w + NE;                       // 102400
    unsigned short* hgB = (unsigned short*)(pp + NB * PCH * 128);  // 4096 bf16
    int* rowptr = (int*)(hgB + 4096);               // 32001 (+3 pad)
    int* cursor = rowptr + TOTALN + 4;              // 32000
    int* bsum   = cursor + TOTALN;                  // 128
    int* csr_src= bsum + 128;                       // 512000
    unsigned short* Wt = (unsigned short*)(csr_src + NE);  // 3*16384 bf16
    unsigned short* fA = (unsigned short*)bufA;
    unsigned short* fB = (unsigned short*)bufB;
    float* p1   = bufA;
    float* p2   = bufA + (long)3 * N_PER * 2048;

    // CSR build
    k_init<<<(TOTALN + 255) / 256, 256, 0, stream>>>(dinv, h1pre);
    k_deg<<<NE / 256, 256, 0, stream>>>(ei, dinv);
    k_scan1<<<125, 256, 0, stream>>>(dinv, rowptr, bsum);
    k_scan2<<<125, 256, 0, stream>>>(rowptr, bsum, cursor);
    k_fill<<<NE / 256, 256, 0, stream>>>(ei, dinv, cursor, csr_src, csr_w);
    k_wcvt3<<<192, 256, 0, stream>>>(Wc1, Wc2, Wc3, Wt);

    // layer 1 (x f32 -> bf16 MFMA)
    k_mm<1><<<500, 256, 0, stream>>>(x, Wt, fB);
    k_gather<0><<<TOTALN / 4, 256, 0, stream>>>(fB, fA, rowptr, csr_src, csr_w, dinv, bc1);
    // layer 2
    k_mm<0><<<500, 256, 0, stream>>>(fA, Wt + 16384, fB);
    k_gather<0><<<TOTALN / 4, 256, 0, stream>>>(fB, fA, rowptr, csr_src, csr_w, dinv, bc2);
    // layer 3 (no relu; bias folded into pool stage 2)
    k_mm<0><<<500, 256, 0, stream>>>(fA, Wt + 32768, fB);
    k_gather<1><<<TOTALN / 4, 256, 0, stream>>>(fB, fA, rowptr, csr_src, csr_w, dinv, nullptr);
    k_pool1<<<NB * PCH, 256, 0, stream>>>(fA, pp);
    k_pool2<<<(NB * 128 + 255) / 256, 256, 0, stream>>>(pp, bc3, hg, hgB);

    // hypernetwork + compute_q
    k_w1<<<NH * W1CH, 256, 0, stream>>>(hgB, Wg1, bg1, act, p1);
    k_red1a<<<96 * 8, 256, 0, stream>>>(p1, h1pre);
    k_w2<<<NH * Dh, 256, 0, stream>>>(hg, Wg2, bg2, h1pre, p2);
    k_out<<<NB, 192, 0, stream>>>(hg, Wg3, bg3, p2, out);
}

// Round 19
// 256.449 us; speedup vs baseline: 1.0985x; 1.0115x over previous
//
#include <hip/hip_runtime.h>
#include <hip/hip_bf16.h>
#include <math.h>

#define NB 32          // graphs
#define N_PER 1000
#define TOTALN 32000
#define NE 512000
#define HID 128
#define Dh 64
#define NH 3
#define EPSV 1e-6f
#define PCH 25         // pool chunks per graph (40 nodes each)
#define W1CH 500       // k_w1 chunks (2 n's each)

typedef __attribute__((ext_vector_type(8))) short bf16x8;
typedef __attribute__((ext_vector_type(4))) float f32x4;

__device__ __forceinline__ float softplusf(float x) {
    return fmaxf(x, 0.0f) + log1pf(expf(-fabsf(x)));
}
__device__ __forceinline__ unsigned short f2b(float f) {
    __hip_bfloat16 h = __float2bfloat16(f);
    return __builtin_bit_cast(unsigned short, h);
}
__device__ __forceinline__ float b2f(unsigned short u) {
    unsigned int x = ((unsigned int)u) << 16;
    return __builtin_bit_cast(float, x);
}
__device__ __forceinline__ void acc8(float* a, uint4 u, float w) {
    a[0] += b2f((unsigned short)(u.x & 0xffff)) * w;
    a[1] += b2f((unsigned short)(u.x >> 16)) * w;
    a[2] += b2f((unsigned short)(u.y & 0xffff)) * w;
    a[3] += b2f((unsigned short)(u.y >> 16)) * w;
    a[4] += b2f((unsigned short)(u.z & 0xffff)) * w;
    a[5] += b2f((unsigned short)(u.z >> 16)) * w;
    a[6] += b2f((unsigned short)(u.w & 0xffff)) * w;
    a[7] += b2f((unsigned short)(u.w >> 16)) * w;
}

// deg init + h1pre zero
__global__ __launch_bounds__(256) void k_init(float* deg, float* h1pre) {
    int i = blockIdx.x * 256 + threadIdx.x;
    if (i < TOTALN) deg[i] = 1.0f;   // self loop
    if (i < 96 * 64) h1pre[i] = 0.f;
}

__global__ __launch_bounds__(256) void k_deg(const int* __restrict__ ei, float* deg) {
    int e = blockIdx.x * 256 + threadIdx.x;
    if (e < NE) atomicAdd(&deg[ei[NE + e]], 1.0f);
}

// fused: dinv = rsqrt(deg) in place + block-local exclusive scan of (deg-1)
__global__ __launch_bounds__(256) void k_scan1(float* __restrict__ deg,
                                               int* __restrict__ rowptr,
                                               int* __restrict__ bsum) {
    __shared__ int sh[256];
    int t = threadIdx.x;
    int i = blockIdx.x * 256 + t;
    float dv = deg[i];
    int v = (int)dv - 1;
    deg[i] = rsqrtf(dv);
    sh[t] = v;
    __syncthreads();
    for (int off = 1; off < 256; off <<= 1) {
        int add = (t >= off) ? sh[t - off] : 0;
        __syncthreads();
        sh[t] += add;
        __syncthreads();
    }
    rowptr[i] = sh[t] - v;
    if (t == 255) bsum[blockIdx.x] = sh[255];
}

// fused: per-block prefix of bsum + global offset add + cursor copy
__global__ __launch_bounds__(256) void k_scan2(int* __restrict__ rowptr,
                                               const int* __restrict__ bsum,
                                               int* __restrict__ cursor) {
    __shared__ int sh[128];
    __shared__ int spre;
    int t = threadIdx.x, bid = blockIdx.x;
    if (t < 125) sh[t] = bsum[t];
    __syncthreads();
    if (t == 0) {
        int run = 0;
        for (int j = 0; j < bid; ++j) run += sh[j];
        spre = run;
    }
    __syncthreads();
    int i = bid * 256 + t;
    int v = rowptr[i] + spre;
    rowptr[i] = v;
    cursor[i] = v;
    if (i == 0) rowptr[TOTALN] = NE;
}

__global__ __launch_bounds__(256) void k_fill(const int* __restrict__ ei,
                                              const float* __restrict__ dinv,
                                              int* __restrict__ cursor,
                                              int* __restrict__ csr_src,
                                              float* __restrict__ csr_w) {
    int e = blockIdx.x * 256 + threadIdx.x;
    if (e < NE) {
        int s = ei[e], d = ei[NE + e];
        int pos = atomicAdd(&cursor[d], 1);
        csr_src[pos] = s;
        csr_w[pos] = dinv[s] * dinv[d];
    }
}

// transpose+convert ALL THREE W[128][128] f32 -> Wt[layer][c][k] bf16
__global__ __launch_bounds__(256) void k_wcvt3(const float* __restrict__ W1,
                                               const float* __restrict__ W2,
                                               const float* __restrict__ W3,
                                               unsigned short* __restrict__ Wt) {
    int i = blockIdx.x * 256 + threadIdx.x;   // 3*16384
    int w = i >> 14, j = i & 16383;
    const float* W = (w == 0) ? W1 : (w == 1) ? W2 : W3;
    int k = j >> 7, c = j & 127;
    Wt[w * 16384 + c * 128 + k] = f2b(W[j]);
}

// Y[32000 x 128](bf16) = X[32000 x 128] @ W ; MFMA 16x16x32 bf16, no LDS.
template<int INF32>
__global__ __launch_bounds__(256) void k_mm(const void* __restrict__ Xv,
                                            const unsigned short* __restrict__ Wt,
                                            unsigned short* __restrict__ Y) {
    int tid = threadIdx.x;
    int wv = tid >> 6, l = tid & 63;
    int row0 = blockIdx.x * 64 + wv * 16;
    int r = l & 15, kc = l >> 4;
    bf16x8 a[4];
    if (INF32) {
        const float* X = (const float*)Xv;
#pragma unroll
        for (int ks = 0; ks < 4; ++ks) {
            const float* p = X + (long)(row0 + r) * 128 + ks * 32 + kc * 8;
            float4 f0 = *(const float4*)p;
            float4 f1 = *(const float4*)(p + 4);
            bf16x8 t;
            t[0] = (short)f2b(f0.x); t[1] = (short)f2b(f0.y);
            t[2] = (short)f2b(f0.z); t[3] = (short)f2b(f0.w);
            t[4] = (short)f2b(f1.x); t[5] = (short)f2b(f1.y);
            t[6] = (short)f2b(f1.z); t[7] = (short)f2b(f1.w);
            a[ks] = t;
        }
    } else {
        const unsigned short* X = (const unsigned short*)Xv;
#pragma unroll
        for (int ks = 0; ks < 4; ++ks)
            a[ks] = *(const bf16x8*)(X + (long)(row0 + r) * 128 + ks * 32 + kc * 8);
    }
    f32x4 acc[8];
#pragma unroll
    for (int nt = 0; nt < 8; ++nt) acc[nt] = (f32x4){0.f, 0.f, 0.f, 0.f};
#pragma unroll
    for (int ks = 0; ks < 4; ++ks) {
#pragma unroll
        for (int nt = 0; nt < 8; ++nt) {
            bf16x8 b = *(const bf16x8*)(Wt + (nt * 16 + r) * 128 + ks * 32 + kc * 8);
            acc[nt] = __builtin_amdgcn_mfma_f32_16x16x32_bf16(a[ks], b, acc[nt], 0, 0, 0);
        }
    }
#pragma unroll
    for (int nt = 0; nt < 8; ++nt)
#pragma unroll
        for (int j = 0; j < 4; ++j)
            Y[(long)(row0 + kc * 4 + j) * 128 + nt * 16 + r] = f2b(acc[nt][j]);
}

// CSR gather, quad-row: wave = 1 node; four 16-lane groups own alternate
// edges; each lane loads uint4 (16B), 16 lanes = one 256B row, one
// instruction = 4 rows. 4-deep ILP => 16 edges in flight/wave. Groups
// combined via shfl_xor(16)+shfl_xor(32); group 0 stores the packed row.
template<int MODE>
__global__ __launch_bounds__(256) void k_gather(const unsigned short* __restrict__ feat,
                                                unsigned short* __restrict__ out,
                                                const int* __restrict__ rowptr,
                                                const int* __restrict__ csr_src,
                                                const float* __restrict__ csr_w,
                                                const float* __restrict__ dinv,
                                                const float* __restrict__ bias) {
    int wid = threadIdx.x >> 6, lane = threadIdx.x & 63;
    int grp = lane >> 4, li = lane & 15;
    int v = blockIdx.x * 4 + wid;
    const uint4* f16 = (const uint4*)feat;   // row = 16 uint4
    float dv = dinv[v];
    uint4 sv = f16[v * 16 + li];
    float a[8] = {0.f, 0.f, 0.f, 0.f, 0.f, 0.f, 0.f, 0.f};
    if (grp == 0) acc8(a, sv, dv * dv);      // self-loop counted once
    int e1 = rowptr[v + 1];
    int i = rowptr[v] + grp;                 // this group's edges: i, i+4, ...
    for (; i + 12 < e1; i += 16) {
        int s0 = csr_src[i], s1 = csr_src[i + 4], s2 = csr_src[i + 8], s3 = csr_src[i + 12];
        float w0 = csr_w[i], w1 = csr_w[i + 4], w2 = csr_w[i + 8], w3 = csr_w[i + 12];
        uint4 u0 = f16[s0 * 16 + li];
        uint4 u1 = f16[s1 * 16 + li];
        uint4 u2 = f16[s2 * 16 + li];
        uint4 u3 = f16[s3 * 16 + li];
        acc8(a, u0, w0);
        acc8(a, u1, w1);
        acc8(a, u2, w2);
        acc8(a, u3, w3);
    }
    for (; i < e1; i += 4) {
        int s = csr_src[i];
        float w = csr_w[i];
        uint4 u = f16[s * 16 + li];
        acc8(a, u, w);
    }
    // combine the four groups
#pragma unroll
    for (int c = 0; c < 8; ++c) {
        a[c] += __shfl_xor(a[c], 16, 64);
        a[c] += __shfl_xor(a[c], 32, 64);
    }
    if (grp == 0) {
        if (MODE == 0) {
            int c0 = li * 8;
#pragma unroll
            for (int c = 0; c < 8; ++c)
                a[c] = fmaxf(a[c] + bias[c0 + c], 0.f);
        }
        uint4 o;
        o.x = (unsigned int)f2b(a[0]) | ((unsigned int)f2b(a[1]) << 16);
        o.y = (unsigned int)f2b(a[2]) | ((unsigned int)f2b(a[3]) << 16);
        o.z = (unsigned int)f2b(a[4]) | ((unsigned int)f2b(a[5]) << 16);
        o.w = (unsigned int)f2b(a[6]) | ((unsigned int)f2b(a[7]) << 16);
        ((uint4*)out)[v * 16 + li] = o;
    }
}

// pool stage 1 (bf16 input)
__global__ __launch_bounds__(256) void k_pool1(const unsigned short* __restrict__ A,
                                               float* __restrict__ pp) {
    __shared__ float sh[256];
    int b = blockIdx.x / PCH, ch = blockIdx.x % PCH;
    int c = threadIdx.x & 127, half = threadIdx.x >> 7;
    float acc = 0.f;
    int n0 = ch * 40;
#pragma unroll 4
    for (int j = half; j < 40; j += 2)
        acc += b2f(A[(long)(b * N_PER + n0 + j) * 128 + c]);
    sh[threadIdx.x] = acc;
    __syncthreads();
    if (threadIdx.x < 128)
        pp[blockIdx.x * 128 + c] = sh[c] + sh[128 + c];
}

// pool stage 2: mean + layer-3 bias; writes hg (f32) + hgB (bf16)
__global__ __launch_bounds__(256) void k_pool2(const float* __restrict__ pp,
                                               const float* __restrict__ bias,
                                               float* __restrict__ hg,
                                               unsigned short* __restrict__ hgB) {
    int i = blockIdx.x * 256 + threadIdx.x;
    if (i >= NB * 128) return;
    int b = i >> 7, c = i & 127;
    float s = 0.f;
#pragma unroll
    for (int ch = 0; ch < PCH; ++ch)
        s += pp[(b * PCH + ch) * 128 + c];
    float v = s * (1.0f / N_PER) + bias[c];
    hg[i] = v;
    hgB[i] = f2b(v);
}

// k_w1 v2 (MFMA + joint 2-n staging): block = (h, chunk of 2 n); 4 waves.
__global__ __launch_bounds__(256) void k_w1(const unsigned short* __restrict__ hgB,
                                            const float* __restrict__ Wg1,
                                            const float* __restrict__ bg1,
                                            const float* __restrict__ actions,
                                            float* __restrict__ p1) {
    __shared__ unsigned short wt[2][64][136];
    int h = blockIdx.x / W1CH, chunk = blockIdx.x % W1CH;
    int tid = threadIdx.x;
    int wv = tid >> 6, l = tid & 63;
    int r = l & 15, kc = l >> 4;
    const long KS = (long)NH * N_PER * Dh;            // 192000
    int n0 = chunk * 2;
    long colbase2 = (long)h * (N_PER * Dh) + (long)n0 * Dh;
    bf16x8 a[2][4];
#pragma unroll
    for (int mt = 0; mt < 2; ++mt)
#pragma unroll
        for (int ks = 0; ks < 4; ++ks)
            a[mt][ks] = *(const bf16x8*)(hgB + (mt * 16 + r) * 128 + ks * 32 + kc * 8);
    int kq = tid >> 5;            // 0..7
    int j = (tid & 31) * 4;       // 0..124, step 4
    int ns = j >> 6, ds = j & 63;
#pragma unroll 4
    for (int it = 0; it < 16; ++it) {
        int k = it * 8 + kq;
        float4 v = *(const float4*)(Wg1 + (long)k * KS + colbase2 + j);
        wt[ns][ds][k]     = f2b(v.x);
        wt[ns][ds + 1][k] = f2b(v.y);
        wt[ns][ds + 2][k] = f2b(v.z);
        wt[ns][ds + 3][k] = f2b(v.w);
    }
    __syncthreads();
#pragma unroll
    for (int nn = 0; nn < 2; ++nn) {
        int n = n0 + nn;
        f32x4 acc0 = (f32x4){0.f, 0.f, 0.f, 0.f};
        f32x4 acc1 = (f32x4){0.f, 0.f, 0.f, 0.f};
#pragma unroll
        for (int ks = 0; ks < 4; ++ks) {
            bf16x8 bb = *(const bf16x8*)&wt[nn][wv * 16 + r][ks * 32 + kc * 8];
            acc0 = __builtin_amdgcn_mfma_f32_16x16x32_bf16(a[0][ks], bb, acc0, 0, 0, 0);
            acc1 = __builtin_amdgcn_mfma_f32_16x16x32_bf16(a[1][ks], bb, acc1, 0, 0, 0);
        }
        float bgv = bg1[colbase2 + nn * 64 + wv * 16 + r];
        float* po = p1 + ((long)h * N_PER + n) * 2048;
#pragma unroll
        for (int jj = 0; jj < 4; ++jj) {
            int b0 = kc * 4 + jj;
            int b1 = 16 + kc * 4 + jj;
            po[b0 * 64 + wv * 16 + r] = softplusf(acc0[jj] + bgv) * actions[b0 * N_PER + n];
            po[b1 * 64 + wv * 16 + r] = softplusf(acc1[jj] + bgv) * actions[b1 * N_PER + n];
        }
    }
}

// red1: grid 96*8; block = (bh, seg of 125 n); atomic-accumulate into h1pre
__global__ __launch_bounds__(256) void k_red1a(const float* __restrict__ p1,
                                               float* __restrict__ h1pre) {
    __shared__ float sh[4][64];
    int bh = blockIdx.x >> 3, seg = blockIdx.x & 7;   // bh = b*3+h
    int b = bh / 3, h = bh % 3;
    int part = threadIdx.x >> 6, d = threadIdx.x & 63;
    const float* base = p1 + (long)h * N_PER * 2048 + b * 64 + d;
    float s = 0.f;
    for (int n = seg * 125 + part; n < seg * 125 + 125; n += 4)
        s += base[(long)n * 2048];
    if (part) sh[part][d] = s;
    __syncthreads();
    if (part == 0)
        atomicAdd(&h1pre[bh * 64 + d], s + sh[1][d] + sh[2][d] + sh[3][d]);
}

// k_w2: SafeSqrt applied on h1pre load
__global__ __launch_bounds__(256) void k_w2(const float* __restrict__ hg,
                                            const float* __restrict__ Wg2,
                                            const float* __restrict__ bg2,
                                            const float* __restrict__ h1pre,
                                            float* __restrict__ p2) {
    __shared__ float hgs[32][128];
    __shared__ float wt[128][64];
    __shared__ float h1s[32];
    int hd = blockIdx.x;
    int tid = threadIdx.x;
    for (int i = 0; i < 16; ++i) {
        int idx = tid + i * 256;
        hgs[idx >> 7][idx & 127] = hg[idx];
    }
    long base = (long)hd * 64;
    for (int i = 0; i < 32; ++i) {
        int idx = tid + i * 256;
        wt[idx >> 6][idx & 63] = Wg2[(long)(idx >> 6) * (NH * Dh * Dh) + base + (idx & 63)];
    }
    int h = hd >> 6, d = hd & 63;
    if (tid < 32)
        h1s[tid] = sqrtf(fmaxf(h1pre[(tid * 3 + h) * 64 + d], 0.f) + EPSV);
    __syncthreads();
    int e = tid & 63, bq = tid >> 6;
    float bgv = bg2[base + e];
    float dot[8];
#pragma unroll
    for (int bi = 0; bi < 8; ++bi) dot[bi] = 0.f;
    for (int k = 0; k < 128; ++k) {
        float w = wt[k][e];
#pragma unroll
        for (int bi = 0; bi < 8; ++bi)
            dot[bi] += hgs[bq * 8 + bi][k] * w;
    }
    float* po = p2 + (long)hd * (32 * 64);
#pragma unroll
    for (int bi = 0; bi < 8; ++bi) {
        int b = bq * 8 + bi;
        po[b * 64 + e] = softplusf(dot[bi] + bgv) * h1s[b];
    }
}

// k_out: red2 (d-sum + SafeLog) folded in
__global__ __launch_bounds__(192) void k_out(const float* __restrict__ hg,
                                             const float* __restrict__ Wg3,
                                             const float* __restrict__ bg3,
                                             const float* __restrict__ p2,
                                             float* __restrict__ out) {
    __shared__ float hgb[128];
    __shared__ float hres[NH];
    int b = blockIdx.x, tid = threadIdx.x;
    if (tid < 128) hgb[tid] = hg[b * 128 + tid];
    __syncthreads();
    int h = tid / 64, e = tid & 63;
    int c = h * 64 + e;
    float s = 0.f;
#pragma unroll 8
    for (int d = 0; d < 64; ++d)
        s += p2[(long)(h * 64 + d) * 2048 + b * 64 + e];
    float h2v = log1pf(fmaxf(s, 0.f));
    float dot = 0.f;
    for (int k = 0; k < 128; ++k)
        dot += hgb[k] * Wg3[k * (NH * Dh) + c];
    float v = softplusf(dot + bg3[c]) * h2v;
    for (int off = 32; off; off >>= 1)
        v += __shfl_down(v, off, 64);
    if (e == 0) hres[h] = v;
    __syncthreads();
    if (tid == 0) out[b] = fminf(fminf(hres[0], hres[1]), hres[2]);
}

extern "C" void kernel_launch(void* const* d_in, const int* in_sizes, int n_in,
                              void* d_out, int out_size, void* d_ws, size_t ws_size,
                              hipStream_t stream) {
    const float* x   = (const float*)d_in[0];
    const int*   ei  = (const int*)d_in[1];
    const float* act = (const float*)d_in[3];
    const float* Wc1 = (const float*)d_in[4];
    const float* bc1 = (const float*)d_in[5];
    const float* Wc2 = (const float*)d_in[6];
    const float* bc2 = (const float*)d_in[7];
    const float* Wc3 = (const float*)d_in[8];
    const float* bc3 = (const float*)d_in[9];
    const float* Wg1 = (const float*)d_in[10];
    const float* bg1 = (const float*)d_in[11];
    const float* Wg2 = (const float*)d_in[12];
    const float* bg2 = (const float*)d_in[13];
    const float* Wg3 = (const float*)d_in[14];
    const float* bg3 = (const float*)d_in[15];
    float* out = (float*)d_out;

    float* ws   = (float*)d_ws;
    float* dinv = ws;                               // 32000 (deg -> dinv in place)
    float* bufA = dinv + TOTALN;                    // feat A (bf16) / p1 lower
    float* bufB = bufA + (long)TOTALN * 128;        // feat B / p1 upper
    float* hg   = bufB + (long)TOTALN * 128;        // 4096
    float* h1pre = hg + 32 * 128;                   // 6144 (atomic accumulator)
    float* csr_w = h1pre + 96 * 64;                 // 512000
    float* pp   = csr_w + NE;                       // 102400
    unsigned short* hgB = (unsigned short*)(pp + NB * PCH * 128);  // 4096 bf16
    int* rowptr = (int*)(hgB + 4096);               // 32001 (+3 pad)
    int* cursor = rowptr + TOTALN + 4;              // 32000
    int* bsum   = cursor + TOTALN;                  // 128
    int* csr_src= bsum + 128;                       // 512000
    unsigned short* Wt = (unsigned short*)(csr_src + NE);  // 3*16384 bf16
    unsigned short* fA = (unsigned short*)bufA;
    unsigned short* fB = (unsigned short*)bufB;
    float* p1   = bufA;
    float* p2   = bufA + (long)3 * N_PER * 2048;

    // CSR build
    k_init<<<(TOTALN + 255) / 256, 256, 0, stream>>>(dinv, h1pre);
    k_deg<<<NE / 256, 256, 0, stream>>>(ei, dinv);
    k_scan1<<<125, 256, 0, stream>>>(dinv, rowptr, bsum);
    k_scan2<<<125, 256, 0, stream>>>(rowptr, bsum, cursor);
    k_fill<<<NE / 256, 256, 0, stream>>>(ei, dinv, cursor, csr_src, csr_w);
    k_wcvt3<<<192, 256, 0, stream>>>(Wc1, Wc2, Wc3, Wt);

    // layer 1 (x f32 -> bf16 MFMA)
    k_mm<1><<<500, 256, 0, stream>>>(x, Wt, fB);
    k_gather<0><<<TOTALN / 4, 256, 0, stream>>>(fB, fA, rowptr, csr_src, csr_w, dinv, bc1);
    // layer 2
    k_mm<0><<<500, 256, 0, stream>>>(fA, Wt + 16384, fB);
    k_gather<0><<<TOTALN / 4, 256, 0, stream>>>(fB, fA, rowptr, csr_src, csr_w, dinv, bc2);
    // layer 3 (no relu; bias folded into pool stage 2)
    k_mm<0><<<500, 256, 0, stream>>>(fA, Wt + 32768, fB);
    k_gather<1><<<TOTALN / 4, 256, 0, stream>>>(fB, fA, rowptr, csr_src, csr_w, dinv, nullptr);
    k_pool1<<<NB * PCH, 256, 0, stream>>>(fA, pp);
    k_pool2<<<(NB * 128 + 255) / 256, 256, 0, stream>>>(pp, bc3, hg, hgB);

    // hypernetwork + compute_q
    k_w1<<<NH * W1CH, 256, 0, stream>>>(hgB, Wg1, bg1, act, p1);
    k_red1a<<<96 * 8, 256, 0, stream>>>(p1, h1pre);
    k_w2<<<NH * Dh, 256, 0, stream>>>(hg, Wg2, bg2, h1pre, p2);
    k_out<<<NB, 192, 0, stream>>>(hg, Wg3, bg3, p2, out);
}

// Round 20
// 250.830 us; speedup vs baseline: 1.1231x; 1.0224x over previous
//
#include <hip/hip_runtime.h>
#include <hip/hip_bf16.h>
#include <hip/hip_fp8.h>
#include <math.h>

#define NB 32          // graphs
#define N_PER 1000
#define TOTALN 32000
#define NE 512000
#define HID 128
#define Dh 64
#define NH 3
#define EPSV 1e-6f
#define PCH 25         // pool chunks per graph (40 nodes each)
#define W1CH 500       // k_w1 chunks (2 n's each)

typedef __attribute__((ext_vector_type(8))) short bf16x8;
typedef __attribute__((ext_vector_type(4))) float f32x4;

__device__ __forceinline__ float softplusf(float x) {
    return fmaxf(x, 0.0f) + log1pf(expf(-fabsf(x)));
}
__device__ __forceinline__ unsigned short f2b(float f) {
    __hip_bfloat16 h = __float2bfloat16(f);
    return __builtin_bit_cast(unsigned short, h);
}
__device__ __forceinline__ float b2f(unsigned short u) {
    unsigned int x = ((unsigned int)u) << 16;
    return __builtin_bit_cast(float, x);
}
__device__ __forceinline__ unsigned char f2q(float f) {
    __hip_fp8_e4m3 q(f);
    return (unsigned char)q.__x;
}
__device__ __forceinline__ float q2f(unsigned char b) {
    __hip_fp8_e4m3 q;
    q.__x = (__hip_fp8_storage_t)b;
    return (float)q;
}
// accumulate 8 fp8 channels (one uint2) * w
__device__ __forceinline__ void acc8q(float* a, uint2 u, float w) {
    a[0] += q2f((unsigned char)(u.x & 0xff)) * w;
    a[1] += q2f((unsigned char)((u.x >> 8) & 0xff)) * w;
    a[2] += q2f((unsigned char)((u.x >> 16) & 0xff)) * w;
    a[3] += q2f((unsigned char)(u.x >> 24)) * w;
    a[4] += q2f((unsigned char)(u.y & 0xff)) * w;
    a[5] += q2f((unsigned char)((u.y >> 8) & 0xff)) * w;
    a[6] += q2f((unsigned char)((u.y >> 16) & 0xff)) * w;
    a[7] += q2f((unsigned char)(u.y >> 24)) * w;
}

// deg init + h1pre zero
__global__ __launch_bounds__(256) void k_init(float* deg, float* h1pre) {
    int i = blockIdx.x * 256 + threadIdx.x;
    if (i < TOTALN) deg[i] = 1.0f;   // self loop
    if (i < 96 * 64) h1pre[i] = 0.f;
}

__global__ __launch_bounds__(256) void k_deg(const int* __restrict__ ei, float* deg) {
    int e = blockIdx.x * 256 + threadIdx.x;
    if (e < NE) atomicAdd(&deg[ei[NE + e]], 1.0f);
}

// fused: dinv = rsqrt(deg) in place + block-local exclusive scan of (deg-1)
__global__ __launch_bounds__(256) void k_scan1(float* __restrict__ deg,
                                               int* __restrict__ rowptr,
                                               int* __restrict__ bsum) {
    __shared__ int sh[256];
    int t = threadIdx.x;
    int i = blockIdx.x * 256 + t;
    float dv = deg[i];
    int v = (int)dv - 1;
    deg[i] = rsqrtf(dv);
    sh[t] = v;
    __syncthreads();
    for (int off = 1; off < 256; off <<= 1) {
        int add = (t >= off) ? sh[t - off] : 0;
        __syncthreads();
        sh[t] += add;
        __syncthreads();
    }
    rowptr[i] = sh[t] - v;
    if (t == 255) bsum[blockIdx.x] = sh[255];
}

// fused: per-block prefix of bsum + global offset add + cursor copy
__global__ __launch_bounds__(256) void k_scan2(int* __restrict__ rowptr,
                                               const int* __restrict__ bsum,
                                               int* __restrict__ cursor) {
    __shared__ int sh[128];
    __shared__ int spre;
    int t = threadIdx.x, bid = blockIdx.x;
    if (t < 125) sh[t] = bsum[t];
    __syncthreads();
    if (t == 0) {
        int run = 0;
        for (int j = 0; j < bid; ++j) run += sh[j];
        spre = run;
    }
    __syncthreads();
    int i = bid * 256 + t;
    int v = rowptr[i] + spre;
    rowptr[i] = v;
    cursor[i] = v;
    if (i == 0) rowptr[TOTALN] = NE;
}

__global__ __launch_bounds__(256) void k_fill(const int* __restrict__ ei,
                                              const float* __restrict__ dinv,
                                              int* __restrict__ cursor,
                                              int* __restrict__ csr_src,
                                              float* __restrict__ csr_w) {
    int e = blockIdx.x * 256 + threadIdx.x;
    if (e < NE) {
        int s = ei[e], d = ei[NE + e];
        int pos = atomicAdd(&cursor[d], 1);
        csr_src[pos] = s;
        csr_w[pos] = dinv[s] * dinv[d];
    }
}

// transpose+convert ALL THREE W[128][128] f32 -> Wt[layer][c][k] bf16
__global__ __launch_bounds__(256) void k_wcvt3(const float* __restrict__ W1,
                                               const float* __restrict__ W2,
                                               const float* __restrict__ W3,
                                               unsigned short* __restrict__ Wt) {
    int i = blockIdx.x * 256 + threadIdx.x;   // 3*16384
    int w = i >> 14, j = i & 16383;
    const float* W = (w == 0) ? W1 : (w == 1) ? W2 : W3;
    int k = j >> 7, c = j & 127;
    Wt[w * 16384 + c * 128 + k] = f2b(W[j]);
}

// Y[32000 x 128](fp8 e4m3) = X[32000 x 128] @ W ; MFMA 16x16x32 bf16, no LDS.
template<int INF32>
__global__ __launch_bounds__(256) void k_mm(const void* __restrict__ Xv,
                                            const unsigned short* __restrict__ Wt,
                                            unsigned char* __restrict__ Y) {
    int tid = threadIdx.x;
    int wv = tid >> 6, l = tid & 63;
    int row0 = blockIdx.x * 64 + wv * 16;
    int r = l & 15, kc = l >> 4;
    bf16x8 a[4];
    if (INF32) {
        const float* X = (const float*)Xv;
#pragma unroll
        for (int ks = 0; ks < 4; ++ks) {
            const float* p = X + (long)(row0 + r) * 128 + ks * 32 + kc * 8;
            float4 f0 = *(const float4*)p;
            float4 f1 = *(const float4*)(p + 4);
            bf16x8 t;
            t[0] = (short)f2b(f0.x); t[1] = (short)f2b(f0.y);
            t[2] = (short)f2b(f0.z); t[3] = (short)f2b(f0.w);
            t[4] = (short)f2b(f1.x); t[5] = (short)f2b(f1.y);
            t[6] = (short)f2b(f1.z); t[7] = (short)f2b(f1.w);
            a[ks] = t;
        }
    } else {
        const unsigned short* X = (const unsigned short*)Xv;
#pragma unroll
        for (int ks = 0; ks < 4; ++ks)
            a[ks] = *(const bf16x8*)(X + (long)(row0 + r) * 128 + ks * 32 + kc * 8);
    }
    f32x4 acc[8];
#pragma unroll
    for (int nt = 0; nt < 8; ++nt) acc[nt] = (f32x4){0.f, 0.f, 0.f, 0.f};
#pragma unroll
    for (int ks = 0; ks < 4; ++ks) {
#pragma unroll
        for (int nt = 0; nt < 8; ++nt) {
            bf16x8 b = *(const bf16x8*)(Wt + (nt * 16 + r) * 128 + ks * 32 + kc * 8);
            acc[nt] = __builtin_amdgcn_mfma_f32_16x16x32_bf16(a[ks], b, acc[nt], 0, 0, 0);
        }
    }
#pragma unroll
    for (int nt = 0; nt < 8; ++nt)
#pragma unroll
        for (int j = 0; j < 4; ++j)
            Y[(long)(row0 + kc * 4 + j) * 128 + nt * 16 + r] = f2q(acc[nt][j]);
}

// CSR gather, quad-row on fp8 rows (128B): wave = 1 node; four 16-lane
// groups own alternate edges; each lane loads uint2 (8B = 8 fp8 channels),
// 16 lanes = one row, one instruction = 4 rows. 16 edges in flight/wave.
// f32 accumulate; OUTPUT stays bf16 (feeds next mm A-operand / pool).
template<int MODE>
__global__ __launch_bounds__(256) void k_gather(const unsigned char* __restrict__ feat,
                                                unsigned short* __restrict__ out,
                                                const int* __restrict__ rowptr,
                                                const int* __restrict__ csr_src,
                                                const float* __restrict__ csr_w,
                                                const float* __restrict__ dinv,
                                                const float* __restrict__ bias) {
    int wid = threadIdx.x >> 6, lane = threadIdx.x & 63;
    int grp = lane >> 4, li = lane & 15;
    int v = blockIdx.x * 4 + wid;
    const uint2* f8 = (const uint2*)feat;   // row = 16 uint2 (128B)
    float dv = dinv[v];
    uint2 sv = f8[v * 16 + li];
    float a[8] = {0.f, 0.f, 0.f, 0.f, 0.f, 0.f, 0.f, 0.f};
    if (grp == 0) acc8q(a, sv, dv * dv);     // self-loop counted once
    int e1 = rowptr[v + 1];
    int i = rowptr[v] + grp;                 // this group's edges: i, i+4, ...
    for (; i + 12 < e1; i += 16) {
        int s0 = csr_src[i], s1 = csr_src[i + 4], s2 = csr_src[i + 8], s3 = csr_src[i + 12];
        float w0 = csr_w[i], w1 = csr_w[i + 4], w2 = csr_w[i + 8], w3 = csr_w[i + 12];
        uint2 u0 = f8[s0 * 16 + li];
        uint2 u1 = f8[s1 * 16 + li];
        uint2 u2 = f8[s2 * 16 + li];
        uint2 u3 = f8[s3 * 16 + li];
        acc8q(a, u0, w0);
        acc8q(a, u1, w1);
        acc8q(a, u2, w2);
        acc8q(a, u3, w3);
    }
    for (; i < e1; i += 4) {
        int s = csr_src[i];
        float w = csr_w[i];
        uint2 u = f8[s * 16 + li];
        acc8q(a, u, w);
    }
    // combine the four groups
#pragma unroll
    for (int c = 0; c < 8; ++c) {
        a[c] += __shfl_xor(a[c], 16, 64);
        a[c] += __shfl_xor(a[c], 32, 64);
    }
    if (grp == 0) {
        if (MODE == 0) {
            int c0 = li * 8;
#pragma unroll
            for (int c = 0; c < 8; ++c)
                a[c] = fmaxf(a[c] + bias[c0 + c], 0.f);
        }
        uint4 o;
        o.x = (unsigned int)f2b(a[0]) | ((unsigned int)f2b(a[1]) << 16);
        o.y = (unsigned int)f2b(a[2]) | ((unsigned int)f2b(a[3]) << 16);
        o.z = (unsigned int)f2b(a[4]) | ((unsigned int)f2b(a[5]) << 16);
        o.w = (unsigned int)f2b(a[6]) | ((unsigned int)f2b(a[7]) << 16);
        ((uint4*)out)[v * 16 + li] = o;
    }
}

// pool stage 1 (bf16 input)
__global__ __launch_bounds__(256) void k_pool1(const unsigned short* __restrict__ A,
                                               float* __restrict__ pp) {
    __shared__ float sh[256];
    int b = blockIdx.x / PCH, ch = blockIdx.x % PCH;
    int c = threadIdx.x & 127, half = threadIdx.x >> 7;
    float acc = 0.f;
    int n0 = ch * 40;
#pragma unroll 4
    for (int j = half; j < 40; j += 2)
        acc += b2f(A[(long)(b * N_PER + n0 + j) * 128 + c]);
    sh[threadIdx.x] = acc;
    __syncthreads();
    if (threadIdx.x < 128)
        pp[blockIdx.x * 128 + c] = sh[c] + sh[128 + c];
}

// pool stage 2: mean + layer-3 bias; writes hg (f32) + hgB (bf16)
__global__ __launch_bounds__(256) void k_pool2(const float* __restrict__ pp,
                                               const float* __restrict__ bias,
                                               float* __restrict__ hg,
                                               unsigned short* __restrict__ hgB) {
    int i = blockIdx.x * 256 + threadIdx.x;
    if (i >= NB * 128) return;
    int b = i >> 7, c = i & 127;
    float s = 0.f;
#pragma unroll
    for (int ch = 0; ch < PCH; ++ch)
        s += pp[(b * PCH + ch) * 128 + c];
    float v = s * (1.0f / N_PER) + bias[c];
    hg[i] = v;
    hgB[i] = f2b(v);
}

// k_w1 v2 (MFMA + joint 2-n staging): block = (h, chunk of 2 n); 4 waves.
__global__ __launch_bounds__(256) void k_w1(const unsigned short* __restrict__ hgB,
                                            const float* __restrict__ Wg1,
                                            const float* __restrict__ bg1,
                                            const float* __restrict__ actions,
                                            float* __restrict__ p1) {
    __shared__ unsigned short wt[2][64][136];
    int h = blockIdx.x / W1CH, chunk = blockIdx.x % W1CH;
    int tid = threadIdx.x;
    int wv = tid >> 6, l = tid & 63;
    int r = l & 15, kc = l >> 4;
    const long KS = (long)NH * N_PER * Dh;            // 192000
    int n0 = chunk * 2;
    long colbase2 = (long)h * (N_PER * Dh) + (long)n0 * Dh;
    bf16x8 a[2][4];
#pragma unroll
    for (int mt = 0; mt < 2; ++mt)
#pragma unroll
        for (int ks = 0; ks < 4; ++ks)
            a[mt][ks] = *(const bf16x8*)(hgB + (mt * 16 + r) * 128 + ks * 32 + kc * 8);
    int kq = tid >> 5;            // 0..7
    int j = (tid & 31) * 4;       // 0..124, step 4
    int ns = j >> 6, ds = j & 63;
#pragma unroll 4
    for (int it = 0; it < 16; ++it) {
        int k = it * 8 + kq;
        float4 v = *(const float4*)(Wg1 + (long)k * KS + colbase2 + j);
        wt[ns][ds][k]     = f2b(v.x);
        wt[ns][ds + 1][k] = f2b(v.y);
        wt[ns][ds + 2][k] = f2b(v.z);
        wt[ns][ds + 3][k] = f2b(v.w);
    }
    __syncthreads();
#pragma unroll
    for (int nn = 0; nn < 2; ++nn) {
        int n = n0 + nn;
        f32x4 acc0 = (f32x4){0.f, 0.f, 0.f, 0.f};
        f32x4 acc1 = (f32x4){0.f, 0.f, 0.f, 0.f};
#pragma unroll
        for (int ks = 0; ks < 4; ++ks) {
            bf16x8 bb = *(const bf16x8*)&wt[nn][wv * 16 + r][ks * 32 + kc * 8];
            acc0 = __builtin_amdgcn_mfma_f32_16x16x32_bf16(a[0][ks], bb, acc0, 0, 0, 0);
            acc1 = __builtin_amdgcn_mfma_f32_16x16x32_bf16(a[1][ks], bb, acc1, 0, 0, 0);
        }
        float bgv = bg1[colbase2 + nn * 64 + wv * 16 + r];
        float* po = p1 + ((long)h * N_PER + n) * 2048;
#pragma unroll
        for (int jj = 0; jj < 4; ++jj) {
            int b0 = kc * 4 + jj;
            int b1 = 16 + kc * 4 + jj;
            po[b0 * 64 + wv * 16 + r] = softplusf(acc0[jj] + bgv) * actions[b0 * N_PER + n];
            po[b1 * 64 + wv * 16 + r] = softplusf(acc1[jj] + bgv) * actions[b1 * N_PER + n];
        }
    }
}

// red1: grid 96*8; block = (bh, seg of 125 n); atomic-accumulate into h1pre
__global__ __launch_bounds__(256) void k_red1a(const float* __restrict__ p1,
                                               float* __restrict__ h1pre) {
    __shared__ float sh[4][64];
    int bh = blockIdx.x >> 3, seg = blockIdx.x & 7;   // bh = b*3+h
    int b = bh / 3, h = bh % 3;
    int part = threadIdx.x >> 6, d = threadIdx.x & 63;
    const float* base = p1 + (long)h * N_PER * 2048 + b * 64 + d;
    float s = 0.f;
    for (int n = seg * 125 + part; n < seg * 125 + 125; n += 4)
        s += base[(long)n * 2048];
    if (part) sh[part][d] = s;
    __syncthreads();
    if (part == 0)
        atomicAdd(&h1pre[bh * 64 + d], s + sh[1][d] + sh[2][d] + sh[3][d]);
}

// k_w2: SafeSqrt applied on h1pre load
__global__ __launch_bounds__(256) void k_w2(const float* __restrict__ hg,
                                            const float* __restrict__ Wg2,
                                            const float* __restrict__ bg2,
                                            const float* __restrict__ h1pre,
                                            float* __restrict__ p2) {
    __shared__ float hgs[32][128];
    __shared__ float wt[128][64];
    __shared__ float h1s[32];
    int hd = blockIdx.x;
    int tid = threadIdx.x;
    for (int i = 0; i < 16; ++i) {
        int idx = tid + i * 256;
        hgs[idx >> 7][idx & 127] = hg[idx];
    }
    long base = (long)hd * 64;
    for (int i = 0; i < 32; ++i) {
        int idx = tid + i * 256;
        wt[idx >> 6][idx & 63] = Wg2[(long)(idx >> 6) * (NH * Dh * Dh) + base + (idx & 63)];
    }
    int h = hd >> 6, d = hd & 63;
    if (tid < 32)
        h1s[tid] = sqrtf(fmaxf(h1pre[(tid * 3 + h) * 64 + d], 0.f) + EPSV);
    __syncthreads();
    int e = tid & 63, bq = tid >> 6;
    float bgv = bg2[base + e];
    float dot[8];
#pragma unroll
    for (int bi = 0; bi < 8; ++bi) dot[bi] = 0.f;
    for (int k = 0; k < 128; ++k) {
        float w = wt[k][e];
#pragma unroll
        for (int bi = 0; bi < 8; ++bi)
            dot[bi] += hgs[bq * 8 + bi][k] * w;
    }
    float* po = p2 + (long)hd * (32 * 64);
#pragma unroll
    for (int bi = 0; bi < 8; ++bi) {
        int b = bq * 8 + bi;
        po[b * 64 + e] = softplusf(dot[bi] + bgv) * h1s[b];
    }
}

// k_out: red2 (d-sum + SafeLog) folded in
__global__ __launch_bounds__(192) void k_out(const float* __restrict__ hg,
                                             const float* __restrict__ Wg3,
                                             const float* __restrict__ bg3,
                                             const float* __restrict__ p2,
                                             float* __restrict__ out) {
    __shared__ float hgb[128];
    __shared__ float hres[NH];
    int b = blockIdx.x, tid = threadIdx.x;
    if (tid < 128) hgb[tid] = hg[b * 128 + tid];
    __syncthreads();
    int h = tid / 64, e = tid & 63;
    int c = h * 64 + e;
    float s = 0.f;
#pragma unroll 8
    for (int d = 0; d < 64; ++d)
        s += p2[(long)(h * 64 + d) * 2048 + b * 64 + e];
    float h2v = log1pf(fmaxf(s, 0.f));
    float dot = 0.f;
    for (int k = 0; k < 128; ++k)
        dot += hgb[k] * Wg3[k * (NH * Dh) + c];
    float v = softplusf(dot + bg3[c]) * h2v;
    for (int off = 32; off; off >>= 1)
        v += __shfl_down(v, off, 64);
    if (e == 0) hres[h] = v;
    __syncthreads();
    if (tid == 0) out[b] = fminf(fminf(hres[0], hres[1]), hres[2]);
}

extern "C" void kernel_launch(void* const* d_in, const int* in_sizes, int n_in,
                              void* d_out, int out_size, void* d_ws, size_t ws_size,
                              hipStream_t stream) {
    const float* x   = (const float*)d_in[0];
    const int*   ei  = (const int*)d_in[1];
    const float* act = (const float*)d_in[3];
    const float* Wc1 = (const float*)d_in[4];
    const float* bc1 = (const float*)d_in[5];
    const float* Wc2 = (const float*)d_in[6];
    const float* bc2 = (const float*)d_in[7];
    const float* Wc3 = (const float*)d_in[8];
    const float* bc3 = (const float*)d_in[9];
    const float* Wg1 = (const float*)d_in[10];
    const float* bg1 = (const float*)d_in[11];
    const float* Wg2 = (const float*)d_in[12];
    const float* bg2 = (const float*)d_in[13];
    const float* Wg3 = (const float*)d_in[14];
    const float* bg3 = (const float*)d_in[15];
    float* out = (float*)d_out;

    float* ws   = (float*)d_ws;
    float* dinv = ws;                               // 32000 (deg -> dinv in place)
    float* bufA = dinv + TOTALN;                    // feat A (bf16) / p1 lower
    float* bufB = bufA + (long)TOTALN * 128;        // feat B (fp8) / p1 upper
    float* hg   = bufB + (long)TOTALN * 128;        // 4096
    float* h1pre = hg + 32 * 128;                   // 6144 (atomic accumulator)
    float* csr_w = h1pre + 96 * 64;                 // 512000
    float* pp   = csr_w + NE;                       // 102400
    unsigned short* hgB = (unsigned short*)(pp + NB * PCH * 128);  // 4096 bf16
    int* rowptr = (int*)(hgB + 4096);               // 32001 (+3 pad)
    int* cursor = rowptr + TOTALN + 4;              // 32000
    int* bsum   = cursor + TOTALN;                  // 128
    int* csr_src= bsum + 128;                       // 512000
    unsigned short* Wt = (unsigned short*)(csr_src + NE);  // 3*16384 bf16
    unsigned short* fA = (unsigned short*)bufA;     // bf16 features
    unsigned char*  fB = (unsigned char*)bufB;      // fp8 features (4.1MB)
    float* p1   = bufA;
    float* p2   = bufA + (long)3 * N_PER * 2048;

    // CSR build
    k_init<<<(TOTALN + 255) / 256, 256, 0, stream>>>(dinv, h1pre);
    k_deg<<<NE / 256, 256, 0, stream>>>(ei, dinv);
    k_scan1<<<125, 256, 0, stream>>>(dinv, rowptr, bsum);
    k_scan2<<<125, 256, 0, stream>>>(rowptr, bsum, cursor);
    k_fill<<<NE / 256, 256, 0, stream>>>(ei, dinv, cursor, csr_src, csr_w);
    k_wcvt3<<<192, 256, 0, stream>>>(Wc1, Wc2, Wc3, Wt);

    // layer 1 (x f32 -> bf16 MFMA -> fp8 out)
    k_mm<1><<<500, 256, 0, stream>>>(x, Wt, fB);
    k_gather<0><<<TOTALN / 4, 256, 0, stream>>>(fB, fA, rowptr, csr_src, csr_w, dinv, bc1);
    // layer 2
    k_mm<0><<<500, 256, 0, stream>>>(fA, Wt + 16384, fB);
    k_gather<0><<<TOTALN / 4, 256, 0, stream>>>(fB, fA, rowptr, csr_src, csr_w, dinv, bc2);
    // layer 3 (no relu; bias folded into pool stage 2)
    k_mm<0><<<500, 256, 0, stream>>>(fA, Wt + 32768, fB);
    k_gather<1><<<TOTALN / 4, 256, 0, stream>>>(fB, fA, rowptr, csr_src, csr_w, dinv, nullptr);
    k_pool1<<<NB * PCH, 256, 0, stream>>>(fA, pp);
    k_pool2<<<(NB * 128 + 255) / 256, 256, 0, stream>>>(pp, bc3, hg, hgB);

    // hypernetwork + compute_q
    k_w1<<<NH * W1CH, 256, 0, stream>>>(hgB, Wg1, bg1, act, p1);
    k_red1a<<<96 * 8, 256, 0, stream>>>(p1, h1pre);
    k_w2<<<NH * Dh, 256, 0, stream>>>(hg, Wg2, bg2, h1pre, p2);
    k_out<<<NB, 192, 0, stream>>>(hg, Wg3, bg3, p2, out);
}

// Round 21
// 250.539 us; speedup vs baseline: 1.1244x; 1.0012x over previous
//
#include <hip/hip_runtime.h>
#include <hip/hip_bf16.h>
#include <hip/hip_fp8.h>
#include <math.h>

#define NB 32          // graphs
#define N_PER 1000
#define TOTALN 32000
#define NE 512000
#define HID 128
#define Dh 64
#define NH 3
#define EPSV 1e-6f
#define PCH 25         // pool chunks per graph (40 nodes each)
#define W1CH 500       // k_w1 chunks (2 n's each)

typedef __attribute__((ext_vector_type(8))) short bf16x8;
typedef __attribute__((ext_vector_type(4))) float f32x4;

__device__ __forceinline__ float softplusf(float x) {
    return fmaxf(x, 0.0f) + log1pf(expf(-fabsf(x)));
}
__device__ __forceinline__ unsigned short f2b(float f) {
    __hip_bfloat16 h = __float2bfloat16(f);
    return __builtin_bit_cast(unsigned short, h);
}
__device__ __forceinline__ float b2f(unsigned short u) {
    unsigned int x = ((unsigned int)u) << 16;
    return __builtin_bit_cast(float, x);
}
__device__ __forceinline__ unsigned char f2q(float f) {
    __hip_fp8_e4m3 q(f);
    return (unsigned char)q.__x;
}
__device__ __forceinline__ float q2f(unsigned char b) {
    __hip_fp8_e4m3 q;
    q.__x = (__hip_fp8_storage_t)b;
    return (float)q;
}
// accumulate 8 fp8 channels (one uint2) * w
__device__ __forceinline__ void acc8q(float* a, uint2 u, float w) {
    a[0] += q2f((unsigned char)(u.x & 0xff)) * w;
    a[1] += q2f((unsigned char)((u.x >> 8) & 0xff)) * w;
    a[2] += q2f((unsigned char)((u.x >> 16) & 0xff)) * w;
    a[3] += q2f((unsigned char)(u.x >> 24)) * w;
    a[4] += q2f((unsigned char)(u.y & 0xff)) * w;
    a[5] += q2f((unsigned char)((u.y >> 8) & 0xff)) * w;
    a[6] += q2f((unsigned char)((u.y >> 16) & 0xff)) * w;
    a[7] += q2f((unsigned char)(u.y >> 24)) * w;
}

// deg init + h1pre zero
__global__ __launch_bounds__(256) void k_init(float* deg, float* h1pre) {
    int i = blockIdx.x * 256 + threadIdx.x;
    if (i < TOTALN) deg[i] = 1.0f;   // self loop
    if (i < 96 * 64) h1pre[i] = 0.f;
}

__global__ __launch_bounds__(256) void k_deg(const int* __restrict__ ei, float* deg) {
    int e = blockIdx.x * 256 + threadIdx.x;
    if (e < NE) atomicAdd(&deg[ei[NE + e]], 1.0f);
}

// fused: dinv = rsqrt(deg) in place + block-local exclusive scan of (deg-1)
__global__ __launch_bounds__(256) void k_scan1(float* __restrict__ deg,
                                               int* __restrict__ rowptr,
                                               int* __restrict__ bsum) {
    __shared__ int sh[256];
    int t = threadIdx.x;
    int i = blockIdx.x * 256 + t;
    float dv = deg[i];
    int v = (int)dv - 1;
    deg[i] = rsqrtf(dv);
    sh[t] = v;
    __syncthreads();
    for (int off = 1; off < 256; off <<= 1) {
        int add = (t >= off) ? sh[t - off] : 0;
        __syncthreads();
        sh[t] += add;
        __syncthreads();
    }
    rowptr[i] = sh[t] - v;
    if (t == 255) bsum[blockIdx.x] = sh[255];
}

// fused: per-block prefix of bsum + global offset add + cursor copy
__global__ __launch_bounds__(256) void k_scan2(int* __restrict__ rowptr,
                                               const int* __restrict__ bsum,
                                               int* __restrict__ cursor) {
    __shared__ int sh[128];
    __shared__ int spre;
    int t = threadIdx.x, bid = blockIdx.x;
    if (t < 125) sh[t] = bsum[t];
    __syncthreads();
    if (t == 0) {
        int run = 0;
        for (int j = 0; j < bid; ++j) run += sh[j];
        spre = run;
    }
    __syncthreads();
    int i = bid * 256 + t;
    int v = rowptr[i] + spre;
    rowptr[i] = v;
    cursor[i] = v;
    if (i == 0) rowptr[TOTALN] = NE;
}

// packed edge record: .x = src node, .y = weight bits
__global__ __launch_bounds__(256) void k_fill(const int* __restrict__ ei,
                                              const float* __restrict__ dinv,
                                              int* __restrict__ cursor,
                                              int2* __restrict__ csr_sw) {
    int e = blockIdx.x * 256 + threadIdx.x;
    if (e < NE) {
        int s = ei[e], d = ei[NE + e];
        int pos = atomicAdd(&cursor[d], 1);
        float w = dinv[s] * dinv[d];
        csr_sw[pos] = make_int2(s, __builtin_bit_cast(int, w));
    }
}

// transpose+convert ALL THREE W[128][128] f32 -> Wt[layer][c][k] bf16
__global__ __launch_bounds__(256) void k_wcvt3(const float* __restrict__ W1,
                                               const float* __restrict__ W2,
                                               const float* __restrict__ W3,
                                               unsigned short* __restrict__ Wt) {
    int i = blockIdx.x * 256 + threadIdx.x;   // 3*16384
    int w = i >> 14, j = i & 16383;
    const float* W = (w == 0) ? W1 : (w == 1) ? W2 : W3;
    int k = j >> 7, c = j & 127;
    Wt[w * 16384 + c * 128 + k] = f2b(W[j]);
}

// Y[32000 x 128](fp8 e4m3) = X[32000 x 128] @ W ; MFMA 16x16x32 bf16, no LDS.
template<int INF32>
__global__ __launch_bounds__(256) void k_mm(const void* __restrict__ Xv,
                                            const unsigned short* __restrict__ Wt,
                                            unsigned char* __restrict__ Y) {
    int tid = threadIdx.x;
    int wv = tid >> 6, l = tid & 63;
    int row0 = blockIdx.x * 64 + wv * 16;
    int r = l & 15, kc = l >> 4;
    bf16x8 a[4];
    if (INF32) {
        const float* X = (const float*)Xv;
#pragma unroll
        for (int ks = 0; ks < 4; ++ks) {
            const float* p = X + (long)(row0 + r) * 128 + ks * 32 + kc * 8;
            float4 f0 = *(const float4*)p;
            float4 f1 = *(const float4*)(p + 4);
            bf16x8 t;
            t[0] = (short)f2b(f0.x); t[1] = (short)f2b(f0.y);
            t[2] = (short)f2b(f0.z); t[3] = (short)f2b(f0.w);
            t[4] = (short)f2b(f1.x); t[5] = (short)f2b(f1.y);
            t[6] = (short)f2b(f1.z); t[7] = (short)f2b(f1.w);
            a[ks] = t;
        }
    } else {
        const unsigned short* X = (const unsigned short*)Xv;
#pragma unroll
        for (int ks = 0; ks < 4; ++ks)
            a[ks] = *(const bf16x8*)(X + (long)(row0 + r) * 128 + ks * 32 + kc * 8);
    }
    f32x4 acc[8];
#pragma unroll
    for (int nt = 0; nt < 8; ++nt) acc[nt] = (f32x4){0.f, 0.f, 0.f, 0.f};
#pragma unroll
    for (int ks = 0; ks < 4; ++ks) {
#pragma unroll
        for (int nt = 0; nt < 8; ++nt) {
            bf16x8 b = *(const bf16x8*)(Wt + (nt * 16 + r) * 128 + ks * 32 + kc * 8);
            acc[nt] = __builtin_amdgcn_mfma_f32_16x16x32_bf16(a[ks], b, acc[nt], 0, 0, 0);
        }
    }
#pragma unroll
    for (int nt = 0; nt < 8; ++nt)
#pragma unroll
        for (int j = 0; j < 4; ++j)
            Y[(long)(row0 + kc * 4 + j) * 128 + nt * 16 + r] = f2q(acc[nt][j]);
}

// CSR gather, quad-row on fp8 rows (128B), packed int2 edge records:
// one 8B broadcast load per edge (src+weight together). 16 edges in
// flight/wave. f32 accumulate; OUTPUT bf16.
template<int MODE>
__global__ __launch_bounds__(256) void k_gather(const unsigned char* __restrict__ feat,
                                                unsigned short* __restrict__ out,
                                                const int* __restrict__ rowptr,
                                                const int2* __restrict__ csr_sw,
                                                const float* __restrict__ dinv,
                                                const float* __restrict__ bias) {
    int wid = threadIdx.x >> 6, lane = threadIdx.x & 63;
    int grp = lane >> 4, li = lane & 15;
    int v = blockIdx.x * 4 + wid;
    const uint2* f8 = (const uint2*)feat;   // row = 16 uint2 (128B)
    float dv = dinv[v];
    uint2 sv = f8[v * 16 + li];
    float a[8] = {0.f, 0.f, 0.f, 0.f, 0.f, 0.f, 0.f, 0.f};
    if (grp == 0) acc8q(a, sv, dv * dv);     // self-loop counted once
    int e1 = rowptr[v + 1];
    int i = rowptr[v] + grp;                 // this group's edges: i, i+4, ...
    for (; i + 12 < e1; i += 16) {
        int2 p0 = csr_sw[i], p1 = csr_sw[i + 4], p2 = csr_sw[i + 8], p3 = csr_sw[i + 12];
        uint2 u0 = f8[p0.x * 16 + li];
        uint2 u1 = f8[p1.x * 16 + li];
        uint2 u2 = f8[p2.x * 16 + li];
        uint2 u3 = f8[p3.x * 16 + li];
        acc8q(a, u0, __builtin_bit_cast(float, p0.y));
        acc8q(a, u1, __builtin_bit_cast(float, p1.y));
        acc8q(a, u2, __builtin_bit_cast(float, p2.y));
        acc8q(a, u3, __builtin_bit_cast(float, p3.y));
    }
    for (; i < e1; i += 4) {
        int2 p = csr_sw[i];
        uint2 u = f8[p.x * 16 + li];
        acc8q(a, u, __builtin_bit_cast(float, p.y));
    }
    // combine the four groups
#pragma unroll
    for (int c = 0; c < 8; ++c) {
        a[c] += __shfl_xor(a[c], 16, 64);
        a[c] += __shfl_xor(a[c], 32, 64);
    }
    if (grp == 0) {
        if (MODE == 0) {
            int c0 = li * 8;
#pragma unroll
            for (int c = 0; c < 8; ++c)
                a[c] = fmaxf(a[c] + bias[c0 + c], 0.f);
        }
        uint4 o;
        o.x = (unsigned int)f2b(a[0]) | ((unsigned int)f2b(a[1]) << 16);
        o.y = (unsigned int)f2b(a[2]) | ((unsigned int)f2b(a[3]) << 16);
        o.z = (unsigned int)f2b(a[4]) | ((unsigned int)f2b(a[5]) << 16);
        o.w = (unsigned int)f2b(a[6]) | ((unsigned int)f2b(a[7]) << 16);
        ((uint4*)out)[v * 16 + li] = o;
    }
}

// pool stage 1 (bf16 input)
__global__ __launch_bounds__(256) void k_pool1(const unsigned short* __restrict__ A,
                                               float* __restrict__ pp) {
    __shared__ float sh[256];
    int b = blockIdx.x / PCH, ch = blockIdx.x % PCH;
    int c = threadIdx.x & 127, half = threadIdx.x >> 7;
    float acc = 0.f;
    int n0 = ch * 40;
#pragma unroll 4
    for (int j = half; j < 40; j += 2)
        acc += b2f(A[(long)(b * N_PER + n0 + j) * 128 + c]);
    sh[threadIdx.x] = acc;
    __syncthreads();
    if (threadIdx.x < 128)
        pp[blockIdx.x * 128 + c] = sh[c] + sh[128 + c];
}

// pool stage 2: mean + layer-3 bias; writes hg (f32) + hgB (bf16)
__global__ __launch_bounds__(256) void k_pool2(const float* __restrict__ pp,
                                               const float* __restrict__ bias,
                                               float* __restrict__ hg,
                                               unsigned short* __restrict__ hgB) {
    int i = blockIdx.x * 256 + threadIdx.x;
    if (i >= NB * 128) return;
    int b = i >> 7, c = i & 127;
    float s = 0.f;
#pragma unroll
    for (int ch = 0; ch < PCH; ++ch)
        s += pp[(b * PCH + ch) * 128 + c];
    float v = s * (1.0f / N_PER) + bias[c];
    hg[i] = v;
    hgB[i] = f2b(v);
}

// k_w1 v2 (MFMA + joint 2-n staging): block = (h, chunk of 2 n); 4 waves.
__global__ __launch_bounds__(256) void k_w1(const unsigned short* __restrict__ hgB,
                                            const float* __restrict__ Wg1,
                                            const float* __restrict__ bg1,
                                            const float* __restrict__ actions,
                                            float* __restrict__ p1) {
    __shared__ unsigned short wt[2][64][136];
    int h = blockIdx.x / W1CH, chunk = blockIdx.x % W1CH;
    int tid = threadIdx.x;
    int wv = tid >> 6, l = tid & 63;
    int r = l & 15, kc = l >> 4;
    const long KS = (long)NH * N_PER * Dh;            // 192000
    int n0 = chunk * 2;
    long colbase2 = (long)h * (N_PER * Dh) + (long)n0 * Dh;
    bf16x8 a[2][4];
#pragma unroll
    for (int mt = 0; mt < 2; ++mt)
#pragma unroll
        for (int ks = 0; ks < 4; ++ks)
            a[mt][ks] = *(const bf16x8*)(hgB + (mt * 16 + r) * 128 + ks * 32 + kc * 8);
    int kq = tid >> 5;            // 0..7
    int j = (tid & 31) * 4;       // 0..124, step 4
    int ns = j >> 6, ds = j & 63;
#pragma unroll 4
    for (int it = 0; it < 16; ++it) {
        int k = it * 8 + kq;
        float4 v = *(const float4*)(Wg1 + (long)k * KS + colbase2 + j);
        wt[ns][ds][k]     = f2b(v.x);
        wt[ns][ds + 1][k] = f2b(v.y);
        wt[ns][ds + 2][k] = f2b(v.z);
        wt[ns][ds + 3][k] = f2b(v.w);
    }
    __syncthreads();
#pragma unroll
    for (int nn = 0; nn < 2; ++nn) {
        int n = n0 + nn;
        f32x4 acc0 = (f32x4){0.f, 0.f, 0.f, 0.f};
        f32x4 acc1 = (f32x4){0.f, 0.f, 0.f, 0.f};
#pragma unroll
        for (int ks = 0; ks < 4; ++ks) {
            bf16x8 bb = *(const bf16x8*)&wt[nn][wv * 16 + r][ks * 32 + kc * 8];
            acc0 = __builtin_amdgcn_mfma_f32_16x16x32_bf16(a[0][ks], bb, acc0, 0, 0, 0);
            acc1 = __builtin_amdgcn_mfma_f32_16x16x32_bf16(a[1][ks], bb, acc1, 0, 0, 0);
        }
        float bgv = bg1[colbase2 + nn * 64 + wv * 16 + r];
        float* po = p1 + ((long)h * N_PER + n) * 2048;
#pragma unroll
        for (int jj = 0; jj < 4; ++jj) {
            int b0 = kc * 4 + jj;
            int b1 = 16 + kc * 4 + jj;
            po[b0 * 64 + wv * 16 + r] = softplusf(acc0[jj] + bgv) * actions[b0 * N_PER + n];
            po[b1 * 64 + wv * 16 + r] = softplusf(acc1[jj] + bgv) * actions[b1 * N_PER + n];
        }
    }
}

// red1: grid 96*8; block = (bh, seg of 125 n); atomic-accumulate into h1pre
__global__ __launch_bounds__(256) void k_red1a(const float* __restrict__ p1,
                                               float* __restrict__ h1pre) {
    __shared__ float sh[4][64];
    int bh = blockIdx.x >> 3, seg = blockIdx.x & 7;   // bh = b*3+h
    int b = bh / 3, h = bh % 3;
    int part = threadIdx.x >> 6, d = threadIdx.x & 63;
    const float* base = p1 + (long)h * N_PER * 2048 + b * 64 + d;
    float s = 0.f;
    for (int n = seg * 125 + part; n < seg * 125 + 125; n += 4)
        s += base[(long)n * 2048];
    if (part) sh[part][d] = s;
    __syncthreads();
    if (part == 0)
        atomicAdd(&h1pre[bh * 64 + d], s + sh[1][d] + sh[2][d] + sh[3][d]);
}

// k_w2: SafeSqrt applied on h1pre load
__global__ __launch_bounds__(256) void k_w2(const float* __restrict__ hg,
                                            const float* __restrict__ Wg2,
                                            const float* __restrict__ bg2,
                                            const float* __restrict__ h1pre,
                                            float* __restrict__ p2) {
    __shared__ float hgs[32][128];
    __shared__ float wt[128][64];
    __shared__ float h1s[32];
    int hd = blockIdx.x;
    int tid = threadIdx.x;
    for (int i = 0; i < 16; ++i) {
        int idx = tid + i * 256;
        hgs[idx >> 7][idx & 127] = hg[idx];
    }
    long base = (long)hd * 64;
    for (int i = 0; i < 32; ++i) {
        int idx = tid + i * 256;
        wt[idx >> 6][idx & 63] = Wg2[(long)(idx >> 6) * (NH * Dh * Dh) + base + (idx & 63)];
    }
    int h = hd >> 6, d = hd & 63;
    if (tid < 32)
        h1s[tid] = sqrtf(fmaxf(h1pre[(tid * 3 + h) * 64 + d], 0.f) + EPSV);
    __syncthreads();
    int e = tid & 63, bq = tid >> 6;
    float bgv = bg2[base + e];
    float dot[8];
#pragma unroll
    for (int bi = 0; bi < 8; ++bi) dot[bi] = 0.f;
    for (int k = 0; k < 128; ++k) {
        float w = wt[k][e];
#pragma unroll
        for (int bi = 0; bi < 8; ++bi)
            dot[bi] += hgs[bq * 8 + bi][k] * w;
    }
    float* po = p2 + (long)hd * (32 * 64);
#pragma unroll
    for (int bi = 0; bi < 8; ++bi) {
        int b = bq * 8 + bi;
        po[b * 64 + e] = softplusf(dot[bi] + bgv) * h1s[b];
    }
}

// k_out: red2 (d-sum + SafeLog) folded in
__global__ __launch_bounds__(192) void k_out(const float* __restrict__ hg,
                                             const float* __restrict__ Wg3,
                                             const float* __restrict__ bg3,
                                             const float* __restrict__ p2,
                                             float* __restrict__ out) {
    __shared__ float hgb[128];
    __shared__ float hres[NH];
    int b = blockIdx.x, tid = threadIdx.x;
    if (tid < 128) hgb[tid] = hg[b * 128 + tid];
    __syncthreads();
    int h = tid / 64, e = tid & 63;
    int c = h * 64 + e;
    float s = 0.f;
#pragma unroll 8
    for (int d = 0; d < 64; ++d)
        s += p2[(long)(h * 64 + d) * 2048 + b * 64 + e];
    float h2v = log1pf(fmaxf(s, 0.f));
    float dot = 0.f;
    for (int k = 0; k < 128; ++k)
        dot += hgb[k] * Wg3[k * (NH * Dh) + c];
    float v = softplusf(dot + bg3[c]) * h2v;
    for (int off = 32; off; off >>= 1)
        v += __shfl_down(v, off, 64);
    if (e == 0) hres[h] = v;
    __syncthreads();
    if (tid == 0) out[b] = fminf(fminf(hres[0], hres[1]), hres[2]);
}

extern "C" void kernel_launch(void* const* d_in, const int* in_sizes, int n_in,
                              void* d_out, int out_size, void* d_ws, size_t ws_size,
                              hipStream_t stream) {
    const float* x   = (const float*)d_in[0];
    const int*   ei  = (const int*)d_in[1];
    const float* act = (const float*)d_in[3];
    const float* Wc1 = (const float*)d_in[4];
    const float* bc1 = (const float*)d_in[5];
    const float* Wc2 = (const float*)d_in[6];
    const float* bc2 = (const float*)d_in[7];
    const float* Wc3 = (const float*)d_in[8];
    const float* bc3 = (const float*)d_in[9];
    const float* Wg1 = (const float*)d_in[10];
    const float* bg1 = (const float*)d_in[11];
    const float* Wg2 = (const float*)d_in[12];
    const float* bg2 = (const float*)d_in[13];
    const float* Wg3 = (const float*)d_in[14];
    const float* bg3 = (const float*)d_in[15];
    float* out = (float*)d_out;

    float* ws   = (float*)d_ws;
    float* dinv = ws;                               // 32000 (deg -> dinv in place)
    float* bufA = dinv + TOTALN;                    // feat A (bf16) / p1 lower
    float* bufB = bufA + (long)TOTALN * 128;        // feat B (fp8) / p1 upper
    float* hg   = bufB + (long)TOTALN * 128;        // 4096
    float* h1pre = hg + 32 * 128;                   // 6144 (atomic accumulator)
    float* pp   = h1pre + 96 * 64;                  // 102400
    unsigned short* hgB = (unsigned short*)(pp + NB * PCH * 128);  // 4096 bf16
    int* rowptr = (int*)(hgB + 4096);               // 32001 (+3 pad)
    int* cursor = rowptr + TOTALN + 4;              // 32000
    int* bsum   = cursor + TOTALN;                  // 128 (+pad)
    int2* csr_sw = (int2*)(bsum + 132);             // 512000 int2 (8B-aligned)
    unsigned short* Wt = (unsigned short*)(csr_sw + NE);  // 3*16384 bf16
    unsigned short* fA = (unsigned short*)bufA;     // bf16 features
    unsigned char*  fB = (unsigned char*)bufB;      // fp8 features (4.1MB)
    float* p1   = bufA;
    float* p2   = bufA + (long)3 * N_PER * 2048;

    // CSR build
    k_init<<<(TOTALN + 255) / 256, 256, 0, stream>>>(dinv, h1pre);
    k_deg<<<NE / 256, 256, 0, stream>>>(ei, dinv);
    k_scan1<<<125, 256, 0, stream>>>(dinv, rowptr, bsum);
    k_scan2<<<125, 256, 0, stream>>>(rowptr, bsum, cursor);
    k_fill<<<NE / 256, 256, 0, stream>>>(ei, dinv, cursor, csr_sw);
    k_wcvt3<<<192, 256, 0, stream>>>(Wc1, Wc2, Wc3, Wt);

    // layer 1 (x f32 -> bf16 MFMA -> fp8 out)
    k_mm<1><<<500, 256, 0, stream>>>(x, Wt, fB);
    k_gather<0><<<TOTALN / 4, 256, 0, stream>>>(fB, fA, rowptr, csr_sw, dinv, bc1);
    // layer 2
    k_mm<0><<<500, 256, 0, stream>>>(fA, Wt + 16384, fB);
    k_gather<0><<<TOTALN / 4, 256, 0, stream>>>(fB, fA, rowptr, csr_sw, dinv, bc2);
    // layer 3 (no relu; bias folded into pool stage 2)
    k_mm<0><<<500, 256, 0, stream>>>(fA, Wt + 32768, fB);
    k_gather<1><<<TOTALN / 4, 256, 0, stream>>>(fB, fA, rowptr, csr_sw, dinv, nullptr);
    k_pool1<<<NB * PCH, 256, 0, stream>>>(fA, pp);
    k_pool2<<<(NB * 128 + 255) / 256, 256, 0, stream>>>(pp, bc3, hg, hgB);

    // hypernetwork + compute_q
    k_w1<<<NH * W1CH, 256, 0, stream>>>(hgB, Wg1, bg1, act, p1);
    k_red1a<<<96 * 8, 256, 0, stream>>>(p1, h1pre);
    k_w2<<<NH * Dh, 256, 0, stream>>>(hg, Wg2, bg2, h1pre, p2);
    k_out<<<NB, 192, 0, stream>>>(hg, Wg3, bg3, p2, out);
}